// Round 9
// baseline (203.812 us; speedup 1.0000x reference)
//
#include <hip/hip_runtime.h>
#include <math.h>

#define NPOL   1000
#define NTICK  98000
#define NCOMM  1000
#define NN     100000
#define NE     1000000
#define NE2    1100000   // NE + NN self-loops
#define NDEGBLK  3907    // ceil(NE/256)
#define NFEATBLK 1563    // ceil(NN*4/256)
#define NFILLBLK 3907
#define NGEMMBLK 12500   // NN/8 nodes per block (2 nodes/wave * 4 waves)

__device__ __forceinline__ unsigned short f2bf(float v) {
    unsigned u = __float_as_uint(v);
    u += 0x7FFFu + ((u >> 16) & 1u);          // round-to-nearest-even
    return (unsigned short)(u >> 16);
}
__device__ __forceinline__ float bf2f(unsigned short s) {
    return __uint_as_float(((unsigned)s) << 16);
}

// ---------------------------------------------------------------------------
// L1 fused: blocks [0,NDEGBLK) do edge degree+rank (atomic-latency-bound,
// ~zero VALU); blocks [NDEGBLK, ...) do node features -> LN -> x (bf16) and
// as1/ad1 via folded weights. The two are data-independent; fusing lets the
// feature work hide entirely under the atomic long pole (R8: 44+43us serial).
__global__ void __launch_bounds__(256) k_deg_feat(
    const int* __restrict__ ei, int* __restrict__ deg, int* __restrict__ ord,
    const float* __restrict__ pol_feat, const int* __restrict__ state_ids,
    const int* __restrict__ sector_ids, const int* __restrict__ industry_ids,
    const float* __restrict__ comp_scalar,
    const float* __restrict__ pol_W, const float* __restrict__ pol_b,
    const float* __restrict__ state_E, const float* __restrict__ sector_E,
    const float* __restrict__ industry_E, const float* __restrict__ comp_W,
    const float* __restrict__ comp_b, const float* __restrict__ comm_E,
    const float* __restrict__ ln_g, const float* __restrict__ ln_b,
    const float* __restrict__ c1_W, const float* __restrict__ c1_as,
    const float* __restrict__ c1_ad,
    unsigned* __restrict__ xbu, float* __restrict__ as1, float* __restrict__ ad1) {
    if (blockIdx.x < NDEGBLK) {
        int e = blockIdx.x * 256 + threadIdx.x;
        if (e < NE) ord[e] = atomicAdd(&deg[ei[NE + e]], 1);
        return;
    }
    __shared__ float sW[2048];      // c1_W (for folding only)
    __shared__ float sAsAd[128];
    __shared__ float sWf[256];      // folded: row i x {Was[0..3], Wad[0..3]}
    __shared__ float sCompW[544];
    __shared__ float sPolW[224];
    __shared__ float sLg[32], sLb[32], sPb[32], sCb[32];
    int t = threadIdx.x;
    for (int i = t; i < 2048; i += 256) sW[i] = c1_W[i];
    for (int i = t; i < 544; i += 256) sCompW[i] = comp_W[i];
    if (t < 224) sPolW[t] = pol_W[t];
    if (t < 64) { sAsAd[t] = c1_as[t]; sAsAd[64 + t] = c1_ad[t]; }
    if (t < 32) { sLg[t] = ln_g[t]; sLb[t] = ln_b[t]; sPb[t] = pol_b[t]; sCb[t] = comp_b[t]; }
    __syncthreads();
    {   // fold: sWf[i*8+c] = sum_f c1_W[i][h*16+f] * (c<4 ? as : ad)[h*16+f], h=c&3
        int i = t >> 3, c = t & 7, h = c & 3;
        const float* av = (c < 4) ? &sAsAd[0] : &sAsAd[64];
        float s = 0.f;
        #pragma unroll
        for (int f = 0; f < 16; ++f) s += sW[i * 64 + h * 16 + f] * av[h * 16 + f];
        sWf[t] = s;
    }
    __syncthreads();
    int tid = (blockIdx.x - NDEGBLK) * 256 + t;
    int n = tid >> 2;
    int q = tid & 3;
    if (n >= NN) return;
    float x[8];
    int jb = q * 8;
    if (n < NPOL) {
        float f[7];
        #pragma unroll
        for (int i = 0; i < 7; ++i) f[i] = pol_feat[n * 7 + i];
        int sid = state_ids[n];
        #pragma unroll
        for (int jj = 0; jj < 8; ++jj) {
            int j = jb + jj;
            float v = sPb[j];
            #pragma unroll
            for (int i = 0; i < 7; ++i) v += f[i] * sPolW[i * 32 + j];
            v = v > 0.f ? v : 0.f;
            x[jj] = v + state_E[sid * 32 + j];
        }
    } else if (n < NPOL + NTICK) {
        int tt = n - NPOL;
        float f[17];
        int sec = sector_ids[tt], ind = industry_ids[tt];
        #pragma unroll
        for (int i = 0; i < 8; ++i) { f[i] = sector_E[sec * 8 + i]; f[8 + i] = industry_E[ind * 8 + i]; }
        f[16] = comp_scalar[tt];
        #pragma unroll
        for (int jj = 0; jj < 8; ++jj) {
            int j = jb + jj;
            float v = sCb[j];
            #pragma unroll
            for (int i = 0; i < 17; ++i) v += f[i] * sCompW[i * 32 + j];
            x[jj] = v > 0.f ? v : 0.f;
        }
    } else {
        int c = n - (NPOL + NTICK);
        float4 a = *(const float4*)&comm_E[c * 32 + jb];
        float4 b = *(const float4*)&comm_E[c * 32 + jb + 4];
        x[0] = a.x; x[1] = a.y; x[2] = a.z; x[3] = a.w;
        x[4] = b.x; x[5] = b.y; x[6] = b.z; x[7] = b.w;
    }
    // LayerNorm via quad (4-thread) reduction: tid=n*4+q so quads are lane 4a..4a+3
    float s1 = 0.f;
    #pragma unroll
    for (int jj = 0; jj < 8; ++jj) s1 += x[jj];
    s1 += __shfl_xor(s1, 1); s1 += __shfl_xor(s1, 2);
    float mu = s1 * (1.f / 32.f);
    float s2 = 0.f;
    #pragma unroll
    for (int jj = 0; jj < 8; ++jj) { float d = x[jj] - mu; s2 += d * d; }
    s2 += __shfl_xor(s2, 1); s2 += __shfl_xor(s2, 2);
    float inv = rsqrtf(s2 * (1.f / 32.f) + 1e-5f);
    #pragma unroll
    for (int jj = 0; jj < 8; ++jj) x[jj] = (x[jj] - mu) * inv * sLg[jb + jj] + sLb[jb + jj];
    // pack bf16 x -> xbu (coalesced uint4 per thread)
    uint4 w;
    w.x = (unsigned)f2bf(x[0]) | ((unsigned)f2bf(x[1]) << 16);
    w.y = (unsigned)f2bf(x[2]) | ((unsigned)f2bf(x[3]) << 16);
    w.z = (unsigned)f2bf(x[4]) | ((unsigned)f2bf(x[5]) << 16);
    w.w = (unsigned)f2bf(x[6]) | ((unsigned)f2bf(x[7]) << 16);
    *(uint4*)&xbu[(unsigned)n * 16u + (unsigned)q * 4u] = w;
    // as1/ad1 partials over this thread's 8 x-dims, then quad reduce
    float pa[8];
    #pragma unroll
    for (int c = 0; c < 8; ++c) pa[c] = 0.f;
    #pragma unroll
    for (int jj = 0; jj < 8; ++jj) {
        float4 wa = *(float4*)&sWf[(jb + jj) * 8];
        float4 wb = *(float4*)&sWf[(jb + jj) * 8 + 4];
        pa[0] = fmaf(x[jj], wa.x, pa[0]); pa[1] = fmaf(x[jj], wa.y, pa[1]);
        pa[2] = fmaf(x[jj], wa.z, pa[2]); pa[3] = fmaf(x[jj], wa.w, pa[3]);
        pa[4] = fmaf(x[jj], wb.x, pa[4]); pa[5] = fmaf(x[jj], wb.y, pa[5]);
        pa[6] = fmaf(x[jj], wb.z, pa[6]); pa[7] = fmaf(x[jj], wb.w, pa[7]);
    }
    #pragma unroll
    for (int c = 0; c < 8; ++c) {
        pa[c] += __shfl_xor(pa[c], 1);
        pa[c] += __shfl_xor(pa[c], 2);
    }
    if (q == 0) {
        *(float4*)&as1[n * 4] = make_float4(pa[0], pa[1], pa[2], pa[3]);
        *(float4*)&ad1[n * 4] = make_float4(pa[4], pa[5], pa[6], pa[7]);
    }
}

// ---------------------------------------------------------------------------
__global__ void k_scan1(const int* __restrict__ deg, int* __restrict__ row_start,
                        int* __restrict__ bsum) {
    __shared__ int tmp[1024];
    int i = blockIdx.x * 1024 + threadIdx.x;
    int v = (i < NN) ? deg[i] + 1 : 0;
    tmp[threadIdx.x] = v;
    __syncthreads();
    for (int off = 1; off < 1024; off <<= 1) {
        int t = (threadIdx.x >= off) ? tmp[threadIdx.x - off] : 0;
        __syncthreads();
        tmp[threadIdx.x] += t;
        __syncthreads();
    }
    if (i < NN) row_start[i] = tmp[threadIdx.x] - v;
    if (threadIdx.x == 1023) bsum[blockIdx.x] = tmp[1023];
}
__global__ void k_scan2(int* __restrict__ bsum, int nb) {
    __shared__ int tmp[128];
    int t = threadIdx.x;
    int v = (t < nb) ? bsum[t] : 0;
    tmp[t] = v;
    __syncthreads();
    for (int off = 1; off < 128; off <<= 1) {
        int u = (t >= off) ? tmp[t - off] : 0;
        __syncthreads();
        tmp[t] += u;
        __syncthreads();
    }
    if (t < nb) bsum[t] = tmp[t] - v;
}
__global__ void k_scan3(int* __restrict__ row_start, const int* __restrict__ bsum) {
    int i = blockIdx.x * blockDim.x + threadIdx.x;
    if (i < NN) row_start[i] += bsum[i >> 10];
}

// ---------------------------------------------------------------------------
// L2 fused: blocks [0,NFILLBLK) do CSR fill (scatter-write-latency-bound);
// blocks [NFILLBLK,...) do the h1 = x @ c1_W GEMM (VALU/LDS-bound, k_mid
// pattern). Independent work -> overlap.
__global__ void __launch_bounds__(256) k_fill_gemm(
    const int* __restrict__ ei, const float* __restrict__ edge_attr,
    const int* __restrict__ row_start, const int* __restrict__ ord,
    const float* __restrict__ c1_eW, const float* __restrict__ c1_ae,
    const float* __restrict__ c2_eW, const float* __restrict__ c2_ae,
    float4* __restrict__ rec,
    const unsigned* __restrict__ xbu, const float* __restrict__ c1_W,
    unsigned short* __restrict__ h1b) {
    int t = threadIdx.x;
    if (blockIdx.x < NFILLBLK) {
        __shared__ float we1s[20];
        __shared__ float we2s[5];
        if (t < 20) {
            int d = t >> 2, h = t & 3;
            float s = 0.f;
            for (int f = 0; f < 16; ++f) s += c1_eW[d * 64 + h * 16 + f] * c1_ae[h * 16 + f];
            we1s[t] = s;
        } else if (t >= 32 && t < 37) {
            int d = t - 32;
            float s = 0.f;
            for (int f = 0; f < 32; ++f) s += c2_eW[d * 32 + f] * c2_ae[f];
            we2s[d] = s;
        }
        __syncthreads();
        int e = blockIdx.x * 256 + t;
        if (e >= NE) return;
        int s = ei[e], d = ei[NE + e];
        int pos = row_start[d] + 1 + ord[e];
        float a[5];
        #pragma unroll
        for (int k = 0; k < 5; ++k) a[k] = edge_attr[e * 5 + k];
        float e0 = 0.f, e1 = 0.f, e2 = 0.f, e3 = 0.f, e4 = 0.f;
        #pragma unroll
        for (int k = 0; k < 5; ++k) {
            e0 += a[k] * we1s[k * 4 + 0];
            e1 += a[k] * we1s[k * 4 + 1];
            e2 += a[k] * we1s[k * 4 + 2];
            e3 += a[k] * we1s[k * 4 + 3];
            e4 += a[k] * we2s[k];
        }
        unsigned u01 = (unsigned)f2bf(e0) | ((unsigned)f2bf(e1) << 16);
        unsigned u23 = (unsigned)f2bf(e2) | ((unsigned)f2bf(e3) << 16);
        rec[pos] = make_float4(__int_as_float(s), __uint_as_float(u01),
                               __uint_as_float(u23), e4);
        return;
    }
    // ---- GEMM part: 2 nodes per wave, lane j owns output cols {j, j+32} ----
    __shared__ float2 Wpk[1024];    // Wpk[k*32+j] = {c1_W[k][j], c1_W[k][j+32]}
    for (int idx = t; idx < 1024; idx += 256) {
        int k = idx >> 5, j = idx & 31;
        Wpk[idx] = make_float2(c1_W[k * 64 + j], c1_W[k * 64 + j + 32]);
    }
    __syncthreads();
    int gwave = (blockIdx.x - NFILLBLK) * 4 + (t >> 6);
    int lane = t & 63;
    int half = lane >> 5, j = lane & 31;
    int n = gwave * 2 + half;
    unsigned u = (j < 16) ? xbu[(unsigned)n * 16u + (unsigned)j] : 0u;
    float a0 = 0.f, a1 = 0.f;
    #pragma unroll
    for (int k2 = 0; k2 < 16; ++k2) {
        unsigned xu = (unsigned)__shfl((int)u, half * 32 + k2, 64);
        float x0 = bf2f((unsigned short)xu);
        float x1 = bf2f((unsigned short)(xu >> 16));
        float2 w0 = Wpk[(2 * k2) * 32 + j];
        float2 w1 = Wpk[(2 * k2 + 1) * 32 + j];
        a0 = fmaf(x0, w0.x, fmaf(x1, w1.x, a0));
        a1 = fmaf(x0, w0.y, fmaf(x1, w1.y, a1));
    }
    h1b[(unsigned)n * 64u + j] = f2bf(a0);
    h1b[(unsigned)n * 64u + 32u + j] = f2bf(a1);
}

// ---------------------------------------------------------------------------
// K6: GAT layer 1. One wave = 2 nodes (32 lanes each); lane owns dims {2j,2j+1}
// via one packed u32 h1b load. Two-phase per 32-edge chunk.
__global__ void __launch_bounds__(256) k_agg1(
    const int* __restrict__ row_start, const int* __restrict__ deg,
    float4* __restrict__ rec,
    const float* __restrict__ as1, const float* __restrict__ ad1,
    const unsigned short* __restrict__ h1b, const float* __restrict__ c1_b,
    unsigned short* __restrict__ x1b) {
    __shared__ float pT[4][2][32][4];
    __shared__ int   srcT[4][2][32];
    int wid = threadIdx.x >> 6;
    int lane = threadIdx.x & 63;
    int half = lane >> 5;
    int j = lane & 31;
    int h = j >> 3;
    int n = blockIdx.x * 8 + wid * 2 + half;
    int base = row_start[n];
    int dg   = deg[n];
    const float4* as1v4 = (const float4*)as1;
    const float4* ad1v4 = (const float4*)ad1;
    float4 adv = ad1v4[n];
    float4 asv = as1v4[n];
    unsigned uself = *(const unsigned*)(h1b + (unsigned)n * 64u + 2u * (unsigned)j);

    float ssum = 0.f, acc0 = 0.f, acc1 = 0.f;
    float aes0 = 0.f, aes1 = 0.f, aes2 = 0.f, aes3 = 0.f, ae2sum = 0.f;

    for (int i0 = 0; i0 < dg; i0 += 32) {
        int clen = dg - i0; if (clen > 32) clen = 32;
        int idx = i0 + j;
        if (idx < dg) {
            float4 r = rec[base + 1 + idx];
            int s = __float_as_int(r.x);
            unsigned u01 = __float_as_uint(r.y), u23 = __float_as_uint(r.z);
            float ae0  = bf2f((unsigned short)u01);
            float ae1v = bf2f((unsigned short)(u01 >> 16));
            float ae2v = bf2f((unsigned short)u23);
            float ae3v = bf2f((unsigned short)(u23 >> 16));
            float4 av = as1v4[s];
            float l0 = av.x + adv.x + ae0;  l0 = l0 > 0.f ? l0 : 0.2f * l0;
            float l1 = av.y + adv.y + ae1v; l1 = l1 > 0.f ? l1 : 0.2f * l1;
            float l2 = av.z + adv.z + ae2v; l2 = l2 > 0.f ? l2 : 0.2f * l2;
            float l3 = av.w + adv.w + ae3v; l3 = l3 > 0.f ? l3 : 0.2f * l3;
            float4 q = make_float4(__expf(l0), __expf(l1), __expf(l2), __expf(l3));
            *(float4*)&pT[wid][half][j][0] = q;
            srcT[wid][half][j] = s;
            aes0 += ae0; aes1 += ae1v; aes2 += ae2v; aes3 += ae3v;
            ae2sum += r.w;
        }
        int i = 0;
        for (; i + 4 <= clen; i += 4) {
            int s0 = srcT[wid][half][i],     s1 = srcT[wid][half][i + 1];
            int s2 = srcT[wid][half][i + 2], s3 = srcT[wid][half][i + 3];
            float q0 = pT[wid][half][i][h],     q1 = pT[wid][half][i + 1][h];
            float q2 = pT[wid][half][i + 2][h], q3 = pT[wid][half][i + 3][h];
            unsigned g0 = *(const unsigned*)(h1b + (unsigned)s0 * 64u + 2u * (unsigned)j);
            unsigned g1 = *(const unsigned*)(h1b + (unsigned)s1 * 64u + 2u * (unsigned)j);
            unsigned g2 = *(const unsigned*)(h1b + (unsigned)s2 * 64u + 2u * (unsigned)j);
            unsigned g3 = *(const unsigned*)(h1b + (unsigned)s3 * 64u + 2u * (unsigned)j);
            ssum += (q0 + q1) + (q2 + q3);
            acc0 = fmaf(q0, bf2f((unsigned short)g0),
                   fmaf(q1, bf2f((unsigned short)g1),
                   fmaf(q2, bf2f((unsigned short)g2),
                   fmaf(q3, bf2f((unsigned short)g3), acc0))));
            acc1 = fmaf(q0, bf2f((unsigned short)(g0 >> 16)),
                   fmaf(q1, bf2f((unsigned short)(g1 >> 16)),
                   fmaf(q2, bf2f((unsigned short)(g2 >> 16)),
                   fmaf(q3, bf2f((unsigned short)(g3 >> 16)), acc1))));
        }
        for (; i < clen; ++i) {
            int s0 = srcT[wid][half][i];
            float q0 = pT[wid][half][i][h];
            unsigned g0 = *(const unsigned*)(h1b + (unsigned)s0 * 64u + 2u * (unsigned)j);
            ssum += q0;
            acc0 = fmaf(q0, bf2f((unsigned short)g0), acc0);
            acc1 = fmaf(q0, bf2f((unsigned short)(g0 >> 16)), acc1);
        }
    }
    #pragma unroll
    for (int m = 1; m < 32; m <<= 1) {
        aes0 += __shfl_xor(aes0, m);
        aes1 += __shfl_xor(aes1, m);
        aes2 += __shfl_xor(aes2, m);
        aes3 += __shfl_xor(aes3, m);
        ae2sum += __shfl_xor(ae2sum, m);
    }
    float invd = 1.f / fmaxf((float)dg, 1.f);
    float aesh = (h == 0) ? aes0 : (h == 1) ? aes1 : (h == 2) ? aes2 : aes3;
    float adh  = (h == 0) ? adv.x : (h == 1) ? adv.y : (h == 2) ? adv.z : adv.w;
    float ash  = (h == 0) ? asv.x : (h == 1) ? asv.y : (h == 2) ? asv.z : asv.w;
    float ls = ash + adh + aesh * invd;
    ls = ls > 0.f ? ls : 0.2f * ls;
    float ps = __expf(ls);
    ssum += ps;
    acc0 = fmaf(ps, bf2f((unsigned short)uself), acc0);
    acc1 = fmaf(ps, bf2f((unsigned short)(uself >> 16)), acc1);
    if (j == 0) {
        rec[base] = make_float4(__int_as_float(n), 0.f, 0.f, ae2sum * invd);
    }
    float inv_s = 1.f / ssum;
    float x0 = acc0 * inv_s + c1_b[2 * j];
    float x1 = acc1 * inv_s + c1_b[2 * j + 1];
    x0 = (x0 > 0.f) ? x0 : (__expf(x0) - 1.f);   // ELU
    x1 = (x1 > 0.f) ? x1 : (__expf(x1) - 1.f);
    unsigned w = (unsigned)f2bf(x0) | ((unsigned)f2bf(x1) << 16);
    *(unsigned*)(x1b + (unsigned)n * 64u + 2u * (unsigned)j) = w;
}

// ---------------------------------------------------------------------------
// K6.5: wave-cooperative GEMV h2 = x1 @ c2_W (64->32) + as2/ad2 scalars.
__global__ void __launch_bounds__(256) k_mid(
    const unsigned short* __restrict__ x1b, const float* __restrict__ c2_W,
    const float* __restrict__ c2_as, const float* __restrict__ c2_ad,
    unsigned short* __restrict__ h2b, float* __restrict__ as2,
    float* __restrict__ ad2) {
    int wave = (blockIdx.x * 256 + threadIdx.x) >> 6;   // 50000 waves exactly
    int lane = threadIdx.x & 63;
    int half = lane >> 5, j = lane & 31;
    int n = wave * 2 + half;
    unsigned u = *(const unsigned*)(x1b + (unsigned)n * 64u + j * 2u);
    float acc = 0.f;
    #pragma unroll
    for (int t = 0; t < 32; ++t) {
        unsigned xu = (unsigned)__shfl((int)u, half * 32 + t, 64);
        float x0 = bf2f((unsigned short)xu);
        float x1 = bf2f((unsigned short)(xu >> 16));
        acc = fmaf(x0, c2_W[(2 * t) * 32 + j], acc);
        acc = fmaf(x1, c2_W[(2 * t + 1) * 32 + j], acc);
    }
    float a = acc * c2_as[j], b = acc * c2_ad[j];
    #pragma unroll
    for (int m = 16; m > 0; m >>= 1) {
        a += __shfl_xor(a, m, 64);
        b += __shfl_xor(b, m, 64);
    }
    if (j == 0) { as2[n] = a; ad2[n] = b; }
    h2b[(unsigned)n * 32u + j] = f2bf(acc);
}

// ---------------------------------------------------------------------------
// K7: GAT layer 2, one 32-lane group per dst, two-phase, writes d_out.
__global__ void __launch_bounds__(256) k_agg2(
    const int* __restrict__ row_start, const int* __restrict__ deg,
    const float4* __restrict__ rec, const float* __restrict__ as2,
    const float* __restrict__ ad2, const unsigned short* __restrict__ h2b,
    const float* __restrict__ c2_b, float* __restrict__ out) {
    __shared__ float2 spT[8][32];
    int t = threadIdx.x;
    int half = t >> 5;
    int l32 = t & 31;
    int n = blockIdx.x * 8 + half;
    int base = row_start[n];
    int len = deg[n] + 1;
    float ad2n = ad2[n];
    float ssum = 0.f, acc = 0.f;
    for (int i0 = 0; i0 < len; i0 += 32) {
        int clen = len - i0; if (clen > 32) clen = 32;
        int idx = i0 + l32;
        float p = 0.f; int s = 0;
        if (idx < len) {
            float4 r = rec[base + idx];
            s = __float_as_int(r.x);
            float l = as2[s] + ad2n + r.w;
            l = l > 0.f ? l : 0.2f * l;
            p = __expf(l);
        }
        ssum += p;
        spT[half][l32] = make_float2(__int_as_float(s), p);
        int i = 0;
        for (; i + 4 <= clen; i += 4) {
            float2 e0 = spT[half][i],     e1 = spT[half][i + 1];
            float2 e2 = spT[half][i + 2], e3 = spT[half][i + 3];
            int s0 = __float_as_int(e0.x), s1 = __float_as_int(e1.x);
            int s2 = __float_as_int(e2.x), s3 = __float_as_int(e3.x);
            float g0 = bf2f(h2b[(unsigned)s0 * 32u + l32]);
            float g1 = bf2f(h2b[(unsigned)s1 * 32u + l32]);
            float g2 = bf2f(h2b[(unsigned)s2 * 32u + l32]);
            float g3 = bf2f(h2b[(unsigned)s3 * 32u + l32]);
            acc = fmaf(e0.y, g0, fmaf(e1.y, g1, fmaf(e2.y, g2, fmaf(e3.y, g3, acc))));
        }
        for (; i < clen; ++i) {
            float2 e0 = spT[half][i];
            int s0 = __float_as_int(e0.x);
            acc = fmaf(e0.y, bf2f(h2b[(unsigned)s0 * 32u + l32]), acc);
        }
    }
    #pragma unroll
    for (int m = 1; m < 32; m <<= 1) ssum += __shfl_xor(ssum, m, 32);
    out[(size_t)n * 32 + l32] = acc / ssum + c2_b[l32];
}

// ---------------------------------------------------------------------------
extern "C" void kernel_launch(void* const* d_in, const int* in_sizes, int n_in,
                              void* d_out, int out_size, void* d_ws, size_t ws_size,
                              hipStream_t stream) {
    const int*   edge_index  = (const int*)  d_in[0];
    const float* edge_attr   = (const float*)d_in[1];
    const float* pol_feat    = (const float*)d_in[2];
    const int*   state_ids   = (const int*)  d_in[3];
    const int*   sector_ids  = (const int*)  d_in[4];
    const int*   industry_ids= (const int*)  d_in[5];
    const float* comp_scalar = (const float*)d_in[6];
    const float* pol_W   = (const float*)d_in[7];
    const float* pol_b   = (const float*)d_in[8];
    const float* state_E = (const float*)d_in[9];
    const float* sector_E= (const float*)d_in[10];
    const float* industry_E=(const float*)d_in[11];
    const float* comp_W  = (const float*)d_in[12];
    const float* comp_b  = (const float*)d_in[13];
    const float* comm_E  = (const float*)d_in[14];
    const float* ln_g    = (const float*)d_in[15];
    const float* ln_b    = (const float*)d_in[16];
    const float* c1_W    = (const float*)d_in[17];
    const float* c1_as   = (const float*)d_in[18];
    const float* c1_ad   = (const float*)d_in[19];
    const float* c1_eW   = (const float*)d_in[20];
    const float* c1_ae   = (const float*)d_in[21];
    const float* c1_b    = (const float*)d_in[22];
    const float* c2_W    = (const float*)d_in[23];
    const float* c2_as   = (const float*)d_in[24];
    const float* c2_ad   = (const float*)d_in[25];
    const float* c2_eW   = (const float*)d_in[26];
    const float* c2_ae   = (const float*)d_in[27];
    const float* c2_b    = (const float*)d_in[28];
    float* out = (float*)d_out;

    char* ws = (char*)d_ws;
    size_t off = 0;
    auto alloc = [&](size_t bytes) { void* p = ws + off; off += (bytes + 255) & ~(size_t)255; return p; };
    int*   deg       = (int*)  alloc(NN * 4);
    int*   ord       = (int*)  alloc((size_t)NE * 4);
    int*   row_start = (int*)  alloc(NN * 4);
    int*   bsum      = (int*)  alloc(128 * 4);
    float4* rec      = (float4*)alloc((size_t)NE2 * 16);
    unsigned* xbu    = (unsigned*)alloc((size_t)NN * 64);        // x bf16 [NN][32]
    unsigned short* h1b = (unsigned short*)alloc((size_t)NN * 64 * 2);
    float* as1       = (float*)alloc((size_t)NN * 4 * 4);
    float* ad1       = (float*)alloc((size_t)NN * 4 * 4);
    unsigned short* x1b = (unsigned short*)alloc((size_t)NN * 64 * 2);
    unsigned short* h2b = (unsigned short*)alloc((size_t)NN * 32 * 2);
    float* as2       = (float*)alloc(NN * 4);
    float* ad2       = (float*)alloc(NN * 4);
    (void)ws_size; (void)in_sizes; (void)n_in; (void)out_size;

    hipMemsetAsync(deg, 0, NN * 4, stream);

    k_deg_feat<<<NDEGBLK + NFEATBLK, 256, 0, stream>>>(
        edge_index, deg, ord,
        pol_feat, state_ids, sector_ids, industry_ids, comp_scalar,
        pol_W, pol_b, state_E, sector_E, industry_E, comp_W, comp_b, comm_E,
        ln_g, ln_b, c1_W, c1_as, c1_ad, xbu, as1, ad1);
    int nblk = (NN + 1023) / 1024;   // 98
    k_scan1<<<nblk, 1024, 0, stream>>>(deg, row_start, bsum);
    k_scan2<<<1, 128, 0, stream>>>(bsum, nblk);
    k_scan3<<<(NN + 255) / 256, 256, 0, stream>>>(row_start, bsum);
    k_fill_gemm<<<NFILLBLK + NGEMMBLK, 256, 0, stream>>>(
        edge_index, edge_attr, row_start, ord, c1_eW, c1_ae, c2_eW, c2_ae, rec,
        xbu, c1_W, h1b);
    k_agg1<<<NN / 8, 256, 0, stream>>>(
        row_start, deg, rec, as1, ad1, h1b, c1_b, x1b);
    k_mid<<<(NN / 2) / 4, 256, 0, stream>>>(          // 50000 waves = 12500 blocks
        x1b, c2_W, c2_as, c2_ad, h2b, as2, ad2);
    k_agg2<<<NN / 8, 256, 0, stream>>>(
        row_start, deg, rec, as2, ad2, h2b, c2_b, out);
}

// Round 10
// 187.304 us; speedup vs baseline: 1.0881x; 1.0881x over previous
//
#include <hip/hip_runtime.h>
#include <math.h>

#define NPOL   1000
#define NTICK  98000
#define NCOMM  1000
#define NN     100000
#define NE     1000000
#define NE2    1100000   // NE + NN self-loops
#define NPREBLK  3907    // ceil(NE/256)
#define NFEATBLK 1563    // ceil(NN*4/256)

__device__ __forceinline__ unsigned short f2bf(float v) {
    unsigned u = __float_as_uint(v);
    u += 0x7FFFu + ((u >> 16) & 1u);          // round-to-nearest-even
    return (unsigned short)(u >> 16);
}
__device__ __forceinline__ float bf2f(unsigned short s) {
    return __uint_as_float(((unsigned)s) << 16);
}

// ---------------------------------------------------------------------------
// K_PRE: per-thread fused. Every thread: issue deg atomic for edge e=tid
// (4-way split counters deg4[d][e&3] to cut same-line serialization), then
// (first 1563 blocks) quad-per-node feature -> LN -> h1 GEMV -> as1/ad1,
// then store ord. Feature/gemm VALU hides under the atomic round-trip.
__global__ void __launch_bounds__(256) k_pre(
    const int* __restrict__ ei, int* __restrict__ deg4, int* __restrict__ ord,
    const float* __restrict__ pol_feat, const int* __restrict__ state_ids,
    const int* __restrict__ sector_ids, const int* __restrict__ industry_ids,
    const float* __restrict__ comp_scalar,
    const float* __restrict__ pol_W, const float* __restrict__ pol_b,
    const float* __restrict__ state_E, const float* __restrict__ sector_E,
    const float* __restrict__ industry_E, const float* __restrict__ comp_W,
    const float* __restrict__ comp_b, const float* __restrict__ comm_E,
    const float* __restrict__ ln_g, const float* __restrict__ ln_b,
    const float* __restrict__ c1_W, const float* __restrict__ c1_as,
    const float* __restrict__ c1_ad,
    unsigned short* __restrict__ h1b, float* __restrict__ as1,
    float* __restrict__ ad1) {
    __shared__ float sW1[2048];     // c1_W 32x64
    __shared__ float sCompW[544];
    __shared__ float sPolW[224];
    __shared__ float sAs[64], sAd[64];
    __shared__ float sLg[32], sLb[32], sPb[32], sCb[32];
    int t = threadIdx.x;
    int e = blockIdx.x * 256 + t;
    // 1) issue the atomic first — its latency is the umbrella
    int ret = 0, d = 0;
    bool hasEdge = (e < NE);
    if (hasEdge) {
        d = ei[NE + e];
        ret = atomicAdd(&deg4[(d << 2) | (e & 3)], 1);
    }
    // 2) feature + h1 work (first NFEATBLK blocks only)
    if (blockIdx.x < NFEATBLK) {
        for (int i = t; i < 2048; i += 256) sW1[i] = c1_W[i];
        for (int i = t; i < 544; i += 256) sCompW[i] = comp_W[i];
        if (t < 224) sPolW[t] = pol_W[t];
        if (t < 64) { sAs[t] = c1_as[t]; sAd[t] = c1_ad[t]; }
        if (t < 32) { sLg[t] = ln_g[t]; sLb[t] = ln_b[t]; sPb[t] = pol_b[t]; sCb[t] = comp_b[t]; }
        __syncthreads();
        int tid = blockIdx.x * 256 + t;
        if (tid < 4 * NN) {
            int n = tid >> 2, q = tid & 3, jb = q * 8;
            float x[8];
            if (n < NPOL) {
                float f[7];
                #pragma unroll
                for (int i = 0; i < 7; ++i) f[i] = pol_feat[n * 7 + i];
                int sid = state_ids[n];
                #pragma unroll
                for (int jj = 0; jj < 8; ++jj) {
                    int j = jb + jj;
                    float v = sPb[j];
                    #pragma unroll
                    for (int i = 0; i < 7; ++i) v += f[i] * sPolW[i * 32 + j];
                    v = v > 0.f ? v : 0.f;
                    x[jj] = v + state_E[sid * 32 + j];
                }
            } else if (n < NPOL + NTICK) {
                int tt = n - NPOL;
                float f[17];
                int sec = sector_ids[tt], ind = industry_ids[tt];
                #pragma unroll
                for (int i = 0; i < 8; ++i) { f[i] = sector_E[sec * 8 + i]; f[8 + i] = industry_E[ind * 8 + i]; }
                f[16] = comp_scalar[tt];
                #pragma unroll
                for (int jj = 0; jj < 8; ++jj) {
                    int j = jb + jj;
                    float v = sCb[j];
                    #pragma unroll
                    for (int i = 0; i < 17; ++i) v += f[i] * sCompW[i * 32 + j];
                    x[jj] = v > 0.f ? v : 0.f;
                }
            } else {
                int c = n - (NPOL + NTICK);
                float4 a = *(const float4*)&comm_E[c * 32 + jb];
                float4 b = *(const float4*)&comm_E[c * 32 + jb + 4];
                x[0] = a.x; x[1] = a.y; x[2] = a.z; x[3] = a.w;
                x[4] = b.x; x[5] = b.y; x[6] = b.z; x[7] = b.w;
            }
            // LayerNorm via quad reduce (quads are lane-aligned: tid%4 == lane%4 pattern)
            float s1 = 0.f;
            #pragma unroll
            for (int jj = 0; jj < 8; ++jj) s1 += x[jj];
            s1 += __shfl_xor(s1, 1); s1 += __shfl_xor(s1, 2);
            float mu = s1 * (1.f / 32.f);
            float s2 = 0.f;
            #pragma unroll
            for (int jj = 0; jj < 8; ++jj) { float dd = x[jj] - mu; s2 += dd * dd; }
            s2 += __shfl_xor(s2, 1); s2 += __shfl_xor(s2, 2);
            float inv = rsqrtf(s2 * (1.f / 32.f) + 1e-5f);
            #pragma unroll
            for (int jj = 0; jj < 8; ++jj) x[jj] = (x[jj] - mu) * inv * sLg[jb + jj] + sLb[jb + jj];
            // h1 cols [q*16, q*16+16): gather quad's x via shfl, W from LDS float4
            float4 acc0 = {0,0,0,0}, acc1 = {0,0,0,0}, acc2 = {0,0,0,0}, acc3 = {0,0,0,0};
            int qb = (t & 63) & ~3;
            int jc = q * 16;
            #pragma unroll
            for (int p = 0; p < 4; ++p) {
                #pragma unroll
                for (int jj = 0; jj < 8; ++jj) {
                    float xs = __shfl(x[jj], qb + p, 64);
                    const float4* wr = (const float4*)&sW1[(p * 8 + jj) * 64 + jc];
                    float4 w0 = wr[0], w1 = wr[1], w2 = wr[2], w3 = wr[3];
                    acc0.x = fmaf(xs, w0.x, acc0.x); acc0.y = fmaf(xs, w0.y, acc0.y);
                    acc0.z = fmaf(xs, w0.z, acc0.z); acc0.w = fmaf(xs, w0.w, acc0.w);
                    acc1.x = fmaf(xs, w1.x, acc1.x); acc1.y = fmaf(xs, w1.y, acc1.y);
                    acc1.z = fmaf(xs, w1.z, acc1.z); acc1.w = fmaf(xs, w1.w, acc1.w);
                    acc2.x = fmaf(xs, w2.x, acc2.x); acc2.y = fmaf(xs, w2.y, acc2.y);
                    acc2.z = fmaf(xs, w2.z, acc2.z); acc2.w = fmaf(xs, w2.w, acc2.w);
                    acc3.x = fmaf(xs, w3.x, acc3.x); acc3.y = fmaf(xs, w3.y, acc3.y);
                    acc3.z = fmaf(xs, w3.z, acc3.z); acc3.w = fmaf(xs, w3.w, acc3.w);
                }
            }
            // as1/ad1 for head q (this thread owns exactly head q's 16 cols)
            const float4* asv = (const float4*)sAs;
            const float4* adv = (const float4*)sAd;
            float4 a0 = asv[q * 4], a1 = asv[q * 4 + 1], a2 = asv[q * 4 + 2], a3 = asv[q * 4 + 3];
            float4 b0 = adv[q * 4], b1 = adv[q * 4 + 1], b2 = adv[q * 4 + 2], b3 = adv[q * 4 + 3];
            float av = acc0.x * a0.x + acc0.y * a0.y + acc0.z * a0.z + acc0.w * a0.w
                     + acc1.x * a1.x + acc1.y * a1.y + acc1.z * a1.z + acc1.w * a1.w
                     + acc2.x * a2.x + acc2.y * a2.y + acc2.z * a2.z + acc2.w * a2.w
                     + acc3.x * a3.x + acc3.y * a3.y + acc3.z * a3.z + acc3.w * a3.w;
            float dv = acc0.x * b0.x + acc0.y * b0.y + acc0.z * b0.z + acc0.w * b0.w
                     + acc1.x * b1.x + acc1.y * b1.y + acc1.z * b1.z + acc1.w * b1.w
                     + acc2.x * b2.x + acc2.y * b2.y + acc2.z * b2.z + acc2.w * b2.w
                     + acc3.x * b3.x + acc3.y * b3.y + acc3.z * b3.z + acc3.w * b3.w;
            as1[tid] = av;
            ad1[tid] = dv;
            // pack 16 bf16 h1 cols -> two uint4 stores (coalesced 128B/quad)
            uint4 w1o, w2o;
            w1o.x = (unsigned)f2bf(acc0.x) | ((unsigned)f2bf(acc0.y) << 16);
            w1o.y = (unsigned)f2bf(acc0.z) | ((unsigned)f2bf(acc0.w) << 16);
            w1o.z = (unsigned)f2bf(acc1.x) | ((unsigned)f2bf(acc1.y) << 16);
            w1o.w = (unsigned)f2bf(acc1.z) | ((unsigned)f2bf(acc1.w) << 16);
            w2o.x = (unsigned)f2bf(acc2.x) | ((unsigned)f2bf(acc2.y) << 16);
            w2o.y = (unsigned)f2bf(acc2.z) | ((unsigned)f2bf(acc2.w) << 16);
            w2o.z = (unsigned)f2bf(acc3.x) | ((unsigned)f2bf(acc3.y) << 16);
            w2o.w = (unsigned)f2bf(acc3.z) | ((unsigned)f2bf(acc3.w) << 16);
            unsigned short* hp = h1b + (unsigned)n * 64u + (unsigned)jc;
            *(uint4*)hp = w1o;
            *(uint4*)(hp + 8) = w2o;
        }
    }
    // 3) land the atomic result
    if (hasEdge) ord[e] = ret;
}

// ---------------------------------------------------------------------------
// scans over deg4 -> degS (per-node degree), row_start, row4 (per-copy bases)
__global__ void k_scan1(const int4* __restrict__ deg4, int* __restrict__ degS,
                        int* __restrict__ row_start, int* __restrict__ bsum) {
    __shared__ int tmp[1024];
    int i = blockIdx.x * 1024 + threadIdx.x;
    int s = 0;
    if (i < NN) {
        int4 d4 = deg4[i];
        s = d4.x + d4.y + d4.z + d4.w;
        degS[i] = s;
    }
    int v = (i < NN) ? s + 1 : 0;
    tmp[threadIdx.x] = v;
    __syncthreads();
    for (int off = 1; off < 1024; off <<= 1) {
        int u = (threadIdx.x >= off) ? tmp[threadIdx.x - off] : 0;
        __syncthreads();
        tmp[threadIdx.x] += u;
        __syncthreads();
    }
    if (i < NN) row_start[i] = tmp[threadIdx.x] - v;
    if (threadIdx.x == 1023) bsum[blockIdx.x] = tmp[1023];
}
__global__ void k_scan2(int* __restrict__ bsum, int nb) {
    __shared__ int tmp[128];
    int t = threadIdx.x;
    int v = (t < nb) ? bsum[t] : 0;
    tmp[t] = v;
    __syncthreads();
    for (int off = 1; off < 128; off <<= 1) {
        int u = (t >= off) ? tmp[t - off] : 0;
        __syncthreads();
        tmp[t] += u;
        __syncthreads();
    }
    if (t < nb) bsum[t] = tmp[t] - v;
}
__global__ void k_scan3(int* __restrict__ row_start, const int* __restrict__ bsum,
                        const int4* __restrict__ deg4, int4* __restrict__ row4) {
    int i = blockIdx.x * blockDim.x + threadIdx.x;
    if (i >= NN) return;
    int rs = row_start[i] + bsum[i >> 10];
    row_start[i] = rs;
    int4 d4 = deg4[i];
    int r0 = rs + 1;
    row4[i] = make_int4(r0, r0 + d4.x, r0 + d4.x + d4.y, r0 + d4.x + d4.y + d4.z);
}

// ---------------------------------------------------------------------------
// K4: CSR fill, atomic-free: pos = row4[d][e&3] + ord[e]. 16B records.
__global__ void __launch_bounds__(256) k_fill(
    const int* __restrict__ ei, const float* __restrict__ edge_attr,
    const int* __restrict__ row4, const int* __restrict__ ord,
    const float* __restrict__ c1_eW, const float* __restrict__ c1_ae,
    const float* __restrict__ c2_eW, const float* __restrict__ c2_ae,
    float4* __restrict__ rec) {
    __shared__ float we1s[20];
    __shared__ float we2s[5];
    int t = threadIdx.x;
    if (t < 20) {
        int d = t >> 2, h = t & 3;
        float s = 0.f;
        for (int f = 0; f < 16; ++f) s += c1_eW[d * 64 + h * 16 + f] * c1_ae[h * 16 + f];
        we1s[t] = s;
    } else if (t >= 32 && t < 37) {
        int d = t - 32;
        float s = 0.f;
        for (int f = 0; f < 32; ++f) s += c2_eW[d * 32 + f] * c2_ae[f];
        we2s[d] = s;
    }
    __syncthreads();
    int e = blockIdx.x * 256 + t;
    if (e >= NE) return;
    int s = ei[e], d = ei[NE + e];
    int pos = row4[(d << 2) | (e & 3)] + ord[e];
    float a[5];
    #pragma unroll
    for (int k = 0; k < 5; ++k) a[k] = edge_attr[e * 5 + k];
    float e0 = 0.f, e1 = 0.f, e2 = 0.f, e3 = 0.f, e4 = 0.f;
    #pragma unroll
    for (int k = 0; k < 5; ++k) {
        e0 += a[k] * we1s[k * 4 + 0];
        e1 += a[k] * we1s[k * 4 + 1];
        e2 += a[k] * we1s[k * 4 + 2];
        e3 += a[k] * we1s[k * 4 + 3];
        e4 += a[k] * we2s[k];
    }
    unsigned u01 = (unsigned)f2bf(e0) | ((unsigned)f2bf(e1) << 16);
    unsigned u23 = (unsigned)f2bf(e2) | ((unsigned)f2bf(e3) << 16);
    rec[pos] = make_float4(__int_as_float(s), __uint_as_float(u01),
                           __uint_as_float(u23), e4);
}

// ---------------------------------------------------------------------------
// K6: GAT layer 1. One wave = 2 nodes (32 lanes each); lane owns dims {2j,2j+1}.
__global__ void __launch_bounds__(256) k_agg1(
    const int* __restrict__ row_start, const int* __restrict__ degS,
    float4* __restrict__ rec,
    const float* __restrict__ as1, const float* __restrict__ ad1,
    const unsigned short* __restrict__ h1b, const float* __restrict__ c1_b,
    unsigned short* __restrict__ x1b) {
    __shared__ float pT[4][2][32][4];
    __shared__ int   srcT[4][2][32];
    int wid = threadIdx.x >> 6;
    int lane = threadIdx.x & 63;
    int half = lane >> 5;
    int j = lane & 31;
    int h = j >> 3;
    int n = blockIdx.x * 8 + wid * 2 + half;
    int base = row_start[n];
    int dg   = degS[n];
    const float4* as1v4 = (const float4*)as1;
    const float4* ad1v4 = (const float4*)ad1;
    float4 adv = ad1v4[n];
    float4 asv = as1v4[n];
    unsigned uself = *(const unsigned*)(h1b + (unsigned)n * 64u + 2u * (unsigned)j);

    float ssum = 0.f, acc0 = 0.f, acc1 = 0.f;
    float aes0 = 0.f, aes1 = 0.f, aes2 = 0.f, aes3 = 0.f, ae2sum = 0.f;

    for (int i0 = 0; i0 < dg; i0 += 32) {
        int clen = dg - i0; if (clen > 32) clen = 32;
        int idx = i0 + j;
        if (idx < dg) {
            float4 r = rec[base + 1 + idx];
            int s = __float_as_int(r.x);
            unsigned u01 = __float_as_uint(r.y), u23 = __float_as_uint(r.z);
            float ae0  = bf2f((unsigned short)u01);
            float ae1v = bf2f((unsigned short)(u01 >> 16));
            float ae2v = bf2f((unsigned short)u23);
            float ae3v = bf2f((unsigned short)(u23 >> 16));
            float4 av = as1v4[s];
            float l0 = av.x + adv.x + ae0;  l0 = l0 > 0.f ? l0 : 0.2f * l0;
            float l1 = av.y + adv.y + ae1v; l1 = l1 > 0.f ? l1 : 0.2f * l1;
            float l2 = av.z + adv.z + ae2v; l2 = l2 > 0.f ? l2 : 0.2f * l2;
            float l3 = av.w + adv.w + ae3v; l3 = l3 > 0.f ? l3 : 0.2f * l3;
            float4 q = make_float4(__expf(l0), __expf(l1), __expf(l2), __expf(l3));
            *(float4*)&pT[wid][half][j][0] = q;
            srcT[wid][half][j] = s;
            aes0 += ae0; aes1 += ae1v; aes2 += ae2v; aes3 += ae3v;
            ae2sum += r.w;
        }
        int i = 0;
        for (; i + 4 <= clen; i += 4) {
            int s0 = srcT[wid][half][i],     s1 = srcT[wid][half][i + 1];
            int s2 = srcT[wid][half][i + 2], s3 = srcT[wid][half][i + 3];
            float q0 = pT[wid][half][i][h],     q1 = pT[wid][half][i + 1][h];
            float q2 = pT[wid][half][i + 2][h], q3 = pT[wid][half][i + 3][h];
            unsigned g0 = *(const unsigned*)(h1b + (unsigned)s0 * 64u + 2u * (unsigned)j);
            unsigned g1 = *(const unsigned*)(h1b + (unsigned)s1 * 64u + 2u * (unsigned)j);
            unsigned g2 = *(const unsigned*)(h1b + (unsigned)s2 * 64u + 2u * (unsigned)j);
            unsigned g3 = *(const unsigned*)(h1b + (unsigned)s3 * 64u + 2u * (unsigned)j);
            ssum += (q0 + q1) + (q2 + q3);
            acc0 = fmaf(q0, bf2f((unsigned short)g0),
                   fmaf(q1, bf2f((unsigned short)g1),
                   fmaf(q2, bf2f((unsigned short)g2),
                   fmaf(q3, bf2f((unsigned short)g3), acc0))));
            acc1 = fmaf(q0, bf2f((unsigned short)(g0 >> 16)),
                   fmaf(q1, bf2f((unsigned short)(g1 >> 16)),
                   fmaf(q2, bf2f((unsigned short)(g2 >> 16)),
                   fmaf(q3, bf2f((unsigned short)(g3 >> 16)), acc1))));
        }
        for (; i < clen; ++i) {
            int s0 = srcT[wid][half][i];
            float q0 = pT[wid][half][i][h];
            unsigned g0 = *(const unsigned*)(h1b + (unsigned)s0 * 64u + 2u * (unsigned)j);
            ssum += q0;
            acc0 = fmaf(q0, bf2f((unsigned short)g0), acc0);
            acc1 = fmaf(q0, bf2f((unsigned short)(g0 >> 16)), acc1);
        }
    }
    #pragma unroll
    for (int m = 1; m < 32; m <<= 1) {
        aes0 += __shfl_xor(aes0, m);
        aes1 += __shfl_xor(aes1, m);
        aes2 += __shfl_xor(aes2, m);
        aes3 += __shfl_xor(aes3, m);
        ae2sum += __shfl_xor(ae2sum, m);
    }
    float invd = 1.f / fmaxf((float)dg, 1.f);
    float aesh = (h == 0) ? aes0 : (h == 1) ? aes1 : (h == 2) ? aes2 : aes3;
    float adh  = (h == 0) ? adv.x : (h == 1) ? adv.y : (h == 2) ? adv.z : adv.w;
    float ash  = (h == 0) ? asv.x : (h == 1) ? asv.y : (h == 2) ? asv.z : asv.w;
    float ls = ash + adh + aesh * invd;
    ls = ls > 0.f ? ls : 0.2f * ls;
    float ps = __expf(ls);
    ssum += ps;
    acc0 = fmaf(ps, bf2f((unsigned short)uself), acc0);
    acc1 = fmaf(ps, bf2f((unsigned short)(uself >> 16)), acc1);
    if (j == 0) {
        rec[base] = make_float4(__int_as_float(n), 0.f, 0.f, ae2sum * invd);
    }
    float inv_s = 1.f / ssum;
    float x0 = acc0 * inv_s + c1_b[2 * j];
    float x1 = acc1 * inv_s + c1_b[2 * j + 1];
    x0 = (x0 > 0.f) ? x0 : (__expf(x0) - 1.f);   // ELU
    x1 = (x1 > 0.f) ? x1 : (__expf(x1) - 1.f);
    unsigned w = (unsigned)f2bf(x0) | ((unsigned)f2bf(x1) << 16);
    *(unsigned*)(x1b + (unsigned)n * 64u + 2u * (unsigned)j) = w;
}

// ---------------------------------------------------------------------------
// K6.5: wave-cooperative GEMV h2 = x1 @ c2_W (64->32) + as2/ad2 scalars.
__global__ void __launch_bounds__(256) k_mid(
    const unsigned short* __restrict__ x1b, const float* __restrict__ c2_W,
    const float* __restrict__ c2_as, const float* __restrict__ c2_ad,
    unsigned short* __restrict__ h2b, float* __restrict__ as2,
    float* __restrict__ ad2) {
    int wave = (blockIdx.x * 256 + threadIdx.x) >> 6;   // 50000 waves exactly
    int lane = threadIdx.x & 63;
    int half = lane >> 5, j = lane & 31;
    int n = wave * 2 + half;
    unsigned u = *(const unsigned*)(x1b + (unsigned)n * 64u + j * 2u);
    float acc = 0.f;
    #pragma unroll
    for (int t = 0; t < 32; ++t) {
        unsigned xu = (unsigned)__shfl((int)u, half * 32 + t, 64);
        float x0 = bf2f((unsigned short)xu);
        float x1 = bf2f((unsigned short)(xu >> 16));
        acc = fmaf(x0, c2_W[(2 * t) * 32 + j], acc);
        acc = fmaf(x1, c2_W[(2 * t + 1) * 32 + j], acc);
    }
    float a = acc * c2_as[j], b = acc * c2_ad[j];
    #pragma unroll
    for (int m = 16; m > 0; m >>= 1) {
        a += __shfl_xor(a, m, 64);
        b += __shfl_xor(b, m, 64);
    }
    if (j == 0) { as2[n] = a; ad2[n] = b; }
    h2b[(unsigned)n * 32u + j] = f2bf(acc);
}

// ---------------------------------------------------------------------------
// K7: GAT layer 2, one 32-lane group per dst, two-phase, writes d_out.
__global__ void __launch_bounds__(256) k_agg2(
    const int* __restrict__ row_start, const int* __restrict__ degS,
    const float4* __restrict__ rec, const float* __restrict__ as2,
    const float* __restrict__ ad2, const unsigned short* __restrict__ h2b,
    const float* __restrict__ c2_b, float* __restrict__ out) {
    __shared__ float2 spT[8][32];
    int t = threadIdx.x;
    int half = t >> 5;
    int l32 = t & 31;
    int n = blockIdx.x * 8 + half;
    int base = row_start[n];
    int len = degS[n] + 1;
    float ad2n = ad2[n];
    float ssum = 0.f, acc = 0.f;
    for (int i0 = 0; i0 < len; i0 += 32) {
        int clen = len - i0; if (clen > 32) clen = 32;
        int idx = i0 + l32;
        float p = 0.f; int s = 0;
        if (idx < len) {
            float4 r = rec[base + idx];
            s = __float_as_int(r.x);
            float l = as2[s] + ad2n + r.w;
            l = l > 0.f ? l : 0.2f * l;
            p = __expf(l);
        }
        ssum += p;
        spT[half][l32] = make_float2(__int_as_float(s), p);
        int i = 0;
        for (; i + 4 <= clen; i += 4) {
            float2 e0 = spT[half][i],     e1 = spT[half][i + 1];
            float2 e2 = spT[half][i + 2], e3 = spT[half][i + 3];
            int s0 = __float_as_int(e0.x), s1 = __float_as_int(e1.x);
            int s2 = __float_as_int(e2.x), s3 = __float_as_int(e3.x);
            float g0 = bf2f(h2b[(unsigned)s0 * 32u + l32]);
            float g1 = bf2f(h2b[(unsigned)s1 * 32u + l32]);
            float g2 = bf2f(h2b[(unsigned)s2 * 32u + l32]);
            float g3 = bf2f(h2b[(unsigned)s3 * 32u + l32]);
            acc = fmaf(e0.y, g0, fmaf(e1.y, g1, fmaf(e2.y, g2, fmaf(e3.y, g3, acc))));
        }
        for (; i < clen; ++i) {
            float2 e0 = spT[half][i];
            int s0 = __float_as_int(e0.x);
            acc = fmaf(e0.y, bf2f(h2b[(unsigned)s0 * 32u + l32]), acc);
        }
    }
    #pragma unroll
    for (int m = 1; m < 32; m <<= 1) ssum += __shfl_xor(ssum, m, 32);
    out[(size_t)n * 32 + l32] = acc / ssum + c2_b[l32];
}

// ---------------------------------------------------------------------------
extern "C" void kernel_launch(void* const* d_in, const int* in_sizes, int n_in,
                              void* d_out, int out_size, void* d_ws, size_t ws_size,
                              hipStream_t stream) {
    const int*   edge_index  = (const int*)  d_in[0];
    const float* edge_attr   = (const float*)d_in[1];
    const float* pol_feat    = (const float*)d_in[2];
    const int*   state_ids   = (const int*)  d_in[3];
    const int*   sector_ids  = (const int*)  d_in[4];
    const int*   industry_ids= (const int*)  d_in[5];
    const float* comp_scalar = (const float*)d_in[6];
    const float* pol_W   = (const float*)d_in[7];
    const float* pol_b   = (const float*)d_in[8];
    const float* state_E = (const float*)d_in[9];
    const float* sector_E= (const float*)d_in[10];
    const float* industry_E=(const float*)d_in[11];
    const float* comp_W  = (const float*)d_in[12];
    const float* comp_b  = (const float*)d_in[13];
    const float* comm_E  = (const float*)d_in[14];
    const float* ln_g    = (const float*)d_in[15];
    const float* ln_b    = (const float*)d_in[16];
    const float* c1_W    = (const float*)d_in[17];
    const float* c1_as   = (const float*)d_in[18];
    const float* c1_ad   = (const float*)d_in[19];
    const float* c1_eW   = (const float*)d_in[20];
    const float* c1_ae   = (const float*)d_in[21];
    const float* c1_b    = (const float*)d_in[22];
    const float* c2_W    = (const float*)d_in[23];
    const float* c2_as   = (const float*)d_in[24];
    const float* c2_ad   = (const float*)d_in[25];
    const float* c2_eW   = (const float*)d_in[26];
    const float* c2_ae   = (const float*)d_in[27];
    const float* c2_b    = (const float*)d_in[28];
    float* out = (float*)d_out;

    char* ws = (char*)d_ws;
    size_t off = 0;
    auto alloc = [&](size_t bytes) { void* p = ws + off; off += (bytes + 255) & ~(size_t)255; return p; };
    int*   deg4      = (int*)  alloc((size_t)NN * 16);
    int*   ord       = (int*)  alloc((size_t)NE * 4);
    int*   row_start = (int*)  alloc(NN * 4);
    int*   degS      = (int*)  alloc(NN * 4);
    int*   row4      = (int*)  alloc((size_t)NN * 16);
    int*   bsum      = (int*)  alloc(128 * 4);
    float4* rec      = (float4*)alloc((size_t)NE2 * 16);
    unsigned short* h1b = (unsigned short*)alloc((size_t)NN * 64 * 2);
    float* as1       = (float*)alloc((size_t)NN * 4 * 4);
    float* ad1       = (float*)alloc((size_t)NN * 4 * 4);
    unsigned short* x1b = (unsigned short*)alloc((size_t)NN * 64 * 2);
    unsigned short* h2b = (unsigned short*)alloc((size_t)NN * 32 * 2);
    float* as2       = (float*)alloc(NN * 4);
    float* ad2       = (float*)alloc(NN * 4);
    (void)ws_size; (void)in_sizes; (void)n_in; (void)out_size;

    hipMemsetAsync(deg4, 0, (size_t)NN * 16, stream);

    k_pre<<<NPREBLK, 256, 0, stream>>>(
        edge_index, deg4, ord,
        pol_feat, state_ids, sector_ids, industry_ids, comp_scalar,
        pol_W, pol_b, state_E, sector_E, industry_E, comp_W, comp_b, comm_E,
        ln_g, ln_b, c1_W, c1_as, c1_ad, h1b, as1, ad1);
    int nblk = (NN + 1023) / 1024;   // 98
    k_scan1<<<nblk, 1024, 0, stream>>>((const int4*)deg4, degS, row_start, bsum);
    k_scan2<<<1, 128, 0, stream>>>(bsum, nblk);
    k_scan3<<<(NN + 255) / 256, 256, 0, stream>>>(row_start, bsum, (const int4*)deg4, (int4*)row4);
    k_fill<<<(NE + 255) / 256, 256, 0, stream>>>(
        edge_index, edge_attr, row4, ord, c1_eW, c1_ae, c2_eW, c2_ae, rec);
    k_agg1<<<NN / 8, 256, 0, stream>>>(
        row_start, degS, rec, as1, ad1, h1b, c1_b, x1b);
    k_mid<<<(NN / 2) / 4, 256, 0, stream>>>(
        x1b, c2_W, c2_as, c2_ad, h2b, as2, ad2);
    k_agg2<<<NN / 8, 256, 0, stream>>>(
        row_start, degS, rec, as2, ad2, h2b, c2_b, out);
}

// Round 11
// 182.628 us; speedup vs baseline: 1.1160x; 1.0256x over previous
//
#include <hip/hip_runtime.h>
#include <math.h>

#define NPOL   1000
#define NTICK  98000
#define NCOMM  1000
#define NN     100000
#define NE     1000000
#define NE2    1100000   // NE + NN self-loops
#define NPREBLK  1563    // grid of k_pre; T = 1563*256 = 400128 threads
#define PRET     400128

__device__ __forceinline__ unsigned short f2bf(float v) {
    unsigned u = __float_as_uint(v);
    u += 0x7FFFu + ((u >> 16) & 1u);          // round-to-nearest-even
    return (unsigned short)(u >> 16);
}
__device__ __forceinline__ float bf2f(unsigned short s) {
    return __uint_as_float(((unsigned)s) << 16);
}

// ---------------------------------------------------------------------------
// K_PRE: 3 edges/thread. Order: stage LDS -> barrier -> issue 3 atomicAdds
// (independent returns, no wait) -> feature/LN/h1 GEMV/as1/ad1 (VALU umbrella
// hides the atomic round trip) -> store ords. R10 lesson: 1 atomic in flight
// per thread caps throughput; barrier placed AFTER atomics forced a vmcnt
// drain, so atomics must be issued after the last __syncthreads.
__global__ void __launch_bounds__(256) k_pre(
    const int* __restrict__ ei, int* __restrict__ deg, int* __restrict__ ord,
    const float* __restrict__ pol_feat, const int* __restrict__ state_ids,
    const int* __restrict__ sector_ids, const int* __restrict__ industry_ids,
    const float* __restrict__ comp_scalar,
    const float* __restrict__ pol_W, const float* __restrict__ pol_b,
    const float* __restrict__ state_E, const float* __restrict__ sector_E,
    const float* __restrict__ industry_E, const float* __restrict__ comp_W,
    const float* __restrict__ comp_b, const float* __restrict__ comm_E,
    const float* __restrict__ ln_g, const float* __restrict__ ln_b,
    const float* __restrict__ c1_W, const float* __restrict__ c1_as,
    const float* __restrict__ c1_ad,
    unsigned short* __restrict__ h1b, float* __restrict__ as1,
    float* __restrict__ ad1) {
    __shared__ float sW1[2048];     // c1_W 32x64
    __shared__ float sCompW[544];
    __shared__ float sPolW[224];
    __shared__ float sAs[64], sAd[64];
    __shared__ float sLg[32], sLb[32], sPb[32], sCb[32];
    int t = threadIdx.x;
    int tid = blockIdx.x * 256 + t;
    // edge dsts (coalesced)
    int e0 = tid, e1 = tid + PRET, e2 = tid + 2 * PRET;
    bool b1 = e1 < NE, b2 = e2 < NE;
    int d0 = ei[NE + e0];
    int d1 = b1 ? ei[NE + e1] : 0;
    int d2 = b2 ? ei[NE + e2] : 0;
    // stage LDS weights
    for (int i = t; i < 2048; i += 256) sW1[i] = c1_W[i];
    for (int i = t; i < 544; i += 256) sCompW[i] = comp_W[i];
    if (t < 224) sPolW[t] = pol_W[t];
    if (t < 64) { sAs[t] = c1_as[t]; sAd[t] = c1_ad[t]; }
    if (t < 32) { sLg[t] = ln_g[t]; sLb[t] = ln_b[t]; sPb[t] = pol_b[t]; sCb[t] = comp_b[t]; }
    __syncthreads();
    // issue all atomics AFTER the barrier; returns consumed only at the end
    int r0 = atomicAdd(&deg[d0], 1);
    int r1 = b1 ? atomicAdd(&deg[d1], 1) : 0;
    int r2 = b2 ? atomicAdd(&deg[d2], 1) : 0;
    // feature + h1 work
    if (tid < 4 * NN) {
        int n = tid >> 2, q = tid & 3, jb = q * 8;
        float x[8];
        if (n < NPOL) {
            float f[7];
            #pragma unroll
            for (int i = 0; i < 7; ++i) f[i] = pol_feat[n * 7 + i];
            int sid = state_ids[n];
            #pragma unroll
            for (int jj = 0; jj < 8; ++jj) {
                int j = jb + jj;
                float v = sPb[j];
                #pragma unroll
                for (int i = 0; i < 7; ++i) v += f[i] * sPolW[i * 32 + j];
                v = v > 0.f ? v : 0.f;
                x[jj] = v + state_E[sid * 32 + j];
            }
        } else if (n < NPOL + NTICK) {
            int tt = n - NPOL;
            float f[17];
            int sec = sector_ids[tt], ind = industry_ids[tt];
            #pragma unroll
            for (int i = 0; i < 8; ++i) { f[i] = sector_E[sec * 8 + i]; f[8 + i] = industry_E[ind * 8 + i]; }
            f[16] = comp_scalar[tt];
            #pragma unroll
            for (int jj = 0; jj < 8; ++jj) {
                int j = jb + jj;
                float v = sCb[j];
                #pragma unroll
                for (int i = 0; i < 17; ++i) v += f[i] * sCompW[i * 32 + j];
                x[jj] = v > 0.f ? v : 0.f;
            }
        } else {
            int c = n - (NPOL + NTICK);
            float4 a = *(const float4*)&comm_E[c * 32 + jb];
            float4 b = *(const float4*)&comm_E[c * 32 + jb + 4];
            x[0] = a.x; x[1] = a.y; x[2] = a.z; x[3] = a.w;
            x[4] = b.x; x[5] = b.y; x[6] = b.z; x[7] = b.w;
        }
        // LayerNorm via quad reduce
        float s1 = 0.f;
        #pragma unroll
        for (int jj = 0; jj < 8; ++jj) s1 += x[jj];
        s1 += __shfl_xor(s1, 1); s1 += __shfl_xor(s1, 2);
        float mu = s1 * (1.f / 32.f);
        float s2 = 0.f;
        #pragma unroll
        for (int jj = 0; jj < 8; ++jj) { float dd = x[jj] - mu; s2 += dd * dd; }
        s2 += __shfl_xor(s2, 1); s2 += __shfl_xor(s2, 2);
        float inv = rsqrtf(s2 * (1.f / 32.f) + 1e-5f);
        #pragma unroll
        for (int jj = 0; jj < 8; ++jj) x[jj] = (x[jj] - mu) * inv * sLg[jb + jj] + sLb[jb + jj];
        // h1 cols [q*16, q*16+16)
        float4 acc0 = {0,0,0,0}, acc1 = {0,0,0,0}, acc2 = {0,0,0,0}, acc3 = {0,0,0,0};
        int qb = (t & 63) & ~3;
        int jc = q * 16;
        #pragma unroll
        for (int p = 0; p < 4; ++p) {
            #pragma unroll
            for (int jj = 0; jj < 8; ++jj) {
                float xs = __shfl(x[jj], qb + p, 64);
                const float4* wr = (const float4*)&sW1[(p * 8 + jj) * 64 + jc];
                float4 w0 = wr[0], w1 = wr[1], w2 = wr[2], w3 = wr[3];
                acc0.x = fmaf(xs, w0.x, acc0.x); acc0.y = fmaf(xs, w0.y, acc0.y);
                acc0.z = fmaf(xs, w0.z, acc0.z); acc0.w = fmaf(xs, w0.w, acc0.w);
                acc1.x = fmaf(xs, w1.x, acc1.x); acc1.y = fmaf(xs, w1.y, acc1.y);
                acc1.z = fmaf(xs, w1.z, acc1.z); acc1.w = fmaf(xs, w1.w, acc1.w);
                acc2.x = fmaf(xs, w2.x, acc2.x); acc2.y = fmaf(xs, w2.y, acc2.y);
                acc2.z = fmaf(xs, w2.z, acc2.z); acc2.w = fmaf(xs, w2.w, acc2.w);
                acc3.x = fmaf(xs, w3.x, acc3.x); acc3.y = fmaf(xs, w3.y, acc3.y);
                acc3.z = fmaf(xs, w3.z, acc3.z); acc3.w = fmaf(xs, w3.w, acc3.w);
            }
        }
        const float4* asv = (const float4*)sAs;
        const float4* adv = (const float4*)sAd;
        float4 a0 = asv[q * 4], a1 = asv[q * 4 + 1], a2 = asv[q * 4 + 2], a3 = asv[q * 4 + 3];
        float4 b0 = adv[q * 4], b1v = adv[q * 4 + 1], b2v = adv[q * 4 + 2], b3 = adv[q * 4 + 3];
        float av = acc0.x * a0.x + acc0.y * a0.y + acc0.z * a0.z + acc0.w * a0.w
                 + acc1.x * a1.x + acc1.y * a1.y + acc1.z * a1.z + acc1.w * a1.w
                 + acc2.x * a2.x + acc2.y * a2.y + acc2.z * a2.z + acc2.w * a2.w
                 + acc3.x * a3.x + acc3.y * a3.y + acc3.z * a3.z + acc3.w * a3.w;
        float dv = acc0.x * b0.x + acc0.y * b0.y + acc0.z * b0.z + acc0.w * b0.w
                 + acc1.x * b1v.x + acc1.y * b1v.y + acc1.z * b1v.z + acc1.w * b1v.w
                 + acc2.x * b2v.x + acc2.y * b2v.y + acc2.z * b2v.z + acc2.w * b2v.w
                 + acc3.x * b3.x + acc3.y * b3.y + acc3.z * b3.z + acc3.w * b3.w;
        as1[tid] = av;
        ad1[tid] = dv;
        uint4 w1o, w2o;
        w1o.x = (unsigned)f2bf(acc0.x) | ((unsigned)f2bf(acc0.y) << 16);
        w1o.y = (unsigned)f2bf(acc0.z) | ((unsigned)f2bf(acc0.w) << 16);
        w1o.z = (unsigned)f2bf(acc1.x) | ((unsigned)f2bf(acc1.y) << 16);
        w1o.w = (unsigned)f2bf(acc1.z) | ((unsigned)f2bf(acc1.w) << 16);
        w2o.x = (unsigned)f2bf(acc2.x) | ((unsigned)f2bf(acc2.y) << 16);
        w2o.y = (unsigned)f2bf(acc2.z) | ((unsigned)f2bf(acc2.w) << 16);
        w2o.z = (unsigned)f2bf(acc3.x) | ((unsigned)f2bf(acc3.y) << 16);
        w2o.w = (unsigned)f2bf(acc3.z) | ((unsigned)f2bf(acc3.w) << 16);
        unsigned short* hp = h1b + (unsigned)n * 64u + (unsigned)jc;
        *(uint4*)hp = w1o;
        *(uint4*)(hp + 8) = w2o;
    }
    // land the atomic results
    ord[e0] = r0;
    if (b1) ord[e1] = r1;
    if (b2) ord[e2] = r2;
}

// ---------------------------------------------------------------------------
__global__ void k_scan1(const int* __restrict__ deg, int* __restrict__ row_start,
                        int* __restrict__ bsum) {
    __shared__ int tmp[1024];
    int i = blockIdx.x * 1024 + threadIdx.x;
    int v = (i < NN) ? deg[i] + 1 : 0;
    tmp[threadIdx.x] = v;
    __syncthreads();
    for (int off = 1; off < 1024; off <<= 1) {
        int u = (threadIdx.x >= off) ? tmp[threadIdx.x - off] : 0;
        __syncthreads();
        tmp[threadIdx.x] += u;
        __syncthreads();
    }
    if (i < NN) row_start[i] = tmp[threadIdx.x] - v;
    if (threadIdx.x == 1023) bsum[blockIdx.x] = tmp[1023];
}
__global__ void k_scan2(int* __restrict__ bsum, int nb) {
    __shared__ int tmp[128];
    int t = threadIdx.x;
    int v = (t < nb) ? bsum[t] : 0;
    tmp[t] = v;
    __syncthreads();
    for (int off = 1; off < 128; off <<= 1) {
        int u = (t >= off) ? tmp[t - off] : 0;
        __syncthreads();
        tmp[t] += u;
        __syncthreads();
    }
    if (t < nb) bsum[t] = tmp[t] - v;
}
__global__ void k_scan3(int* __restrict__ row_start, const int* __restrict__ bsum) {
    int i = blockIdx.x * blockDim.x + threadIdx.x;
    if (i < NN) row_start[i] += bsum[i >> 10];
}

// ---------------------------------------------------------------------------
// K4: CSR fill, atomic-free: pos = row_start[d] + 1 + ord[e]. 16B records.
__global__ void __launch_bounds__(256) k_fill(
    const int* __restrict__ ei, const float* __restrict__ edge_attr,
    const int* __restrict__ row_start, const int* __restrict__ ord,
    const float* __restrict__ c1_eW, const float* __restrict__ c1_ae,
    const float* __restrict__ c2_eW, const float* __restrict__ c2_ae,
    float4* __restrict__ rec) {
    __shared__ float we1s[20];
    __shared__ float we2s[5];
    int t = threadIdx.x;
    if (t < 20) {
        int d = t >> 2, h = t & 3;
        float s = 0.f;
        for (int f = 0; f < 16; ++f) s += c1_eW[d * 64 + h * 16 + f] * c1_ae[h * 16 + f];
        we1s[t] = s;
    } else if (t >= 32 && t < 37) {
        int d = t - 32;
        float s = 0.f;
        for (int f = 0; f < 32; ++f) s += c2_eW[d * 32 + f] * c2_ae[f];
        we2s[d] = s;
    }
    __syncthreads();
    int e = blockIdx.x * 256 + t;
    if (e >= NE) return;
    int s = ei[e], d = ei[NE + e];
    int pos = row_start[d] + 1 + ord[e];
    float a[5];
    #pragma unroll
    for (int k = 0; k < 5; ++k) a[k] = edge_attr[e * 5 + k];
    float e0 = 0.f, e1 = 0.f, e2 = 0.f, e3 = 0.f, e4 = 0.f;
    #pragma unroll
    for (int k = 0; k < 5; ++k) {
        e0 += a[k] * we1s[k * 4 + 0];
        e1 += a[k] * we1s[k * 4 + 1];
        e2 += a[k] * we1s[k * 4 + 2];
        e3 += a[k] * we1s[k * 4 + 3];
        e4 += a[k] * we2s[k];
    }
    unsigned u01 = (unsigned)f2bf(e0) | ((unsigned)f2bf(e1) << 16);
    unsigned u23 = (unsigned)f2bf(e2) | ((unsigned)f2bf(e3) << 16);
    rec[pos] = make_float4(__int_as_float(s), __uint_as_float(u01),
                           __uint_as_float(u23), e4);
}

// ---------------------------------------------------------------------------
// K6: GAT layer 1. One wave = 2 nodes (32 lanes each); lane owns dims {2j,2j+1}.
__global__ void __launch_bounds__(256) k_agg1(
    const int* __restrict__ row_start, const int* __restrict__ deg,
    float4* __restrict__ rec,
    const float* __restrict__ as1, const float* __restrict__ ad1,
    const unsigned short* __restrict__ h1b, const float* __restrict__ c1_b,
    unsigned short* __restrict__ x1b) {
    __shared__ float pT[4][2][32][4];
    __shared__ int   srcT[4][2][32];
    int wid = threadIdx.x >> 6;
    int lane = threadIdx.x & 63;
    int half = lane >> 5;
    int j = lane & 31;
    int h = j >> 3;
    int n = blockIdx.x * 8 + wid * 2 + half;
    int base = row_start[n];
    int dg   = deg[n];
    const float4* as1v4 = (const float4*)as1;
    const float4* ad1v4 = (const float4*)ad1;
    float4 adv = ad1v4[n];
    float4 asv = as1v4[n];
    unsigned uself = *(const unsigned*)(h1b + (unsigned)n * 64u + 2u * (unsigned)j);

    float ssum = 0.f, acc0 = 0.f, acc1 = 0.f;
    float aes0 = 0.f, aes1 = 0.f, aes2 = 0.f, aes3 = 0.f, ae2sum = 0.f;

    for (int i0 = 0; i0 < dg; i0 += 32) {
        int clen = dg - i0; if (clen > 32) clen = 32;
        int idx = i0 + j;
        if (idx < dg) {
            float4 r = rec[base + 1 + idx];
            int s = __float_as_int(r.x);
            unsigned u01 = __float_as_uint(r.y), u23 = __float_as_uint(r.z);
            float ae0  = bf2f((unsigned short)u01);
            float ae1v = bf2f((unsigned short)(u01 >> 16));
            float ae2v = bf2f((unsigned short)u23);
            float ae3v = bf2f((unsigned short)(u23 >> 16));
            float4 av = as1v4[s];
            float l0 = av.x + adv.x + ae0;  l0 = l0 > 0.f ? l0 : 0.2f * l0;
            float l1 = av.y + adv.y + ae1v; l1 = l1 > 0.f ? l1 : 0.2f * l1;
            float l2 = av.z + adv.z + ae2v; l2 = l2 > 0.f ? l2 : 0.2f * l2;
            float l3 = av.w + adv.w + ae3v; l3 = l3 > 0.f ? l3 : 0.2f * l3;
            float4 q = make_float4(__expf(l0), __expf(l1), __expf(l2), __expf(l3));
            *(float4*)&pT[wid][half][j][0] = q;
            srcT[wid][half][j] = s;
            aes0 += ae0; aes1 += ae1v; aes2 += ae2v; aes3 += ae3v;
            ae2sum += r.w;
        }
        int i = 0;
        for (; i + 4 <= clen; i += 4) {
            int s0 = srcT[wid][half][i],     s1 = srcT[wid][half][i + 1];
            int s2 = srcT[wid][half][i + 2], s3 = srcT[wid][half][i + 3];
            float q0 = pT[wid][half][i][h],     q1 = pT[wid][half][i + 1][h];
            float q2 = pT[wid][half][i + 2][h], q3 = pT[wid][half][i + 3][h];
            unsigned g0 = *(const unsigned*)(h1b + (unsigned)s0 * 64u + 2u * (unsigned)j);
            unsigned g1 = *(const unsigned*)(h1b + (unsigned)s1 * 64u + 2u * (unsigned)j);
            unsigned g2 = *(const unsigned*)(h1b + (unsigned)s2 * 64u + 2u * (unsigned)j);
            unsigned g3 = *(const unsigned*)(h1b + (unsigned)s3 * 64u + 2u * (unsigned)j);
            ssum += (q0 + q1) + (q2 + q3);
            acc0 = fmaf(q0, bf2f((unsigned short)g0),
                   fmaf(q1, bf2f((unsigned short)g1),
                   fmaf(q2, bf2f((unsigned short)g2),
                   fmaf(q3, bf2f((unsigned short)g3), acc0))));
            acc1 = fmaf(q0, bf2f((unsigned short)(g0 >> 16)),
                   fmaf(q1, bf2f((unsigned short)(g1 >> 16)),
                   fmaf(q2, bf2f((unsigned short)(g2 >> 16)),
                   fmaf(q3, bf2f((unsigned short)(g3 >> 16)), acc1))));
        }
        for (; i < clen; ++i) {
            int s0 = srcT[wid][half][i];
            float q0 = pT[wid][half][i][h];
            unsigned g0 = *(const unsigned*)(h1b + (unsigned)s0 * 64u + 2u * (unsigned)j);
            ssum += q0;
            acc0 = fmaf(q0, bf2f((unsigned short)g0), acc0);
            acc1 = fmaf(q0, bf2f((unsigned short)(g0 >> 16)), acc1);
        }
    }
    #pragma unroll
    for (int m = 1; m < 32; m <<= 1) {
        aes0 += __shfl_xor(aes0, m);
        aes1 += __shfl_xor(aes1, m);
        aes2 += __shfl_xor(aes2, m);
        aes3 += __shfl_xor(aes3, m);
        ae2sum += __shfl_xor(ae2sum, m);
    }
    float invd = 1.f / fmaxf((float)dg, 1.f);
    float aesh = (h == 0) ? aes0 : (h == 1) ? aes1 : (h == 2) ? aes2 : aes3;
    float adh  = (h == 0) ? adv.x : (h == 1) ? adv.y : (h == 2) ? adv.z : adv.w;
    float ash  = (h == 0) ? asv.x : (h == 1) ? asv.y : (h == 2) ? asv.z : asv.w;
    float ls = ash + adh + aesh * invd;
    ls = ls > 0.f ? ls : 0.2f * ls;
    float ps = __expf(ls);
    ssum += ps;
    acc0 = fmaf(ps, bf2f((unsigned short)uself), acc0);
    acc1 = fmaf(ps, bf2f((unsigned short)(uself >> 16)), acc1);
    if (j == 0) {
        rec[base] = make_float4(__int_as_float(n), 0.f, 0.f, ae2sum * invd);
    }
    float inv_s = 1.f / ssum;
    float x0 = acc0 * inv_s + c1_b[2 * j];
    float x1 = acc1 * inv_s + c1_b[2 * j + 1];
    x0 = (x0 > 0.f) ? x0 : (__expf(x0) - 1.f);   // ELU
    x1 = (x1 > 0.f) ? x1 : (__expf(x1) - 1.f);
    unsigned w = (unsigned)f2bf(x0) | ((unsigned)f2bf(x1) << 16);
    *(unsigned*)(x1b + (unsigned)n * 64u + 2u * (unsigned)j) = w;
}

// ---------------------------------------------------------------------------
// K6.5: wave-cooperative GEMV h2 = x1 @ c2_W (64->32) + as2/ad2 scalars.
__global__ void __launch_bounds__(256) k_mid(
    const unsigned short* __restrict__ x1b, const float* __restrict__ c2_W,
    const float* __restrict__ c2_as, const float* __restrict__ c2_ad,
    unsigned short* __restrict__ h2b, float* __restrict__ as2,
    float* __restrict__ ad2) {
    int wave = (blockIdx.x * 256 + threadIdx.x) >> 6;   // 50000 waves exactly
    int lane = threadIdx.x & 63;
    int half = lane >> 5, j = lane & 31;
    int n = wave * 2 + half;
    unsigned u = *(const unsigned*)(x1b + (unsigned)n * 64u + j * 2u);
    float acc = 0.f;
    #pragma unroll
    for (int t = 0; t < 32; ++t) {
        unsigned xu = (unsigned)__shfl((int)u, half * 32 + t, 64);
        float x0 = bf2f((unsigned short)xu);
        float x1 = bf2f((unsigned short)(xu >> 16));
        acc = fmaf(x0, c2_W[(2 * t) * 32 + j], acc);
        acc = fmaf(x1, c2_W[(2 * t + 1) * 32 + j], acc);
    }
    float a = acc * c2_as[j], b = acc * c2_ad[j];
    #pragma unroll
    for (int m = 16; m > 0; m >>= 1) {
        a += __shfl_xor(a, m, 64);
        b += __shfl_xor(b, m, 64);
    }
    if (j == 0) { as2[n] = a; ad2[n] = b; }
    h2b[(unsigned)n * 32u + j] = f2bf(acc);
}

// ---------------------------------------------------------------------------
// K7: GAT layer 2, one 32-lane group per dst, two-phase, writes d_out.
__global__ void __launch_bounds__(256) k_agg2(
    const int* __restrict__ row_start, const int* __restrict__ deg,
    const float4* __restrict__ rec, const float* __restrict__ as2,
    const float* __restrict__ ad2, const unsigned short* __restrict__ h2b,
    const float* __restrict__ c2_b, float* __restrict__ out) {
    __shared__ float2 spT[8][32];
    int t = threadIdx.x;
    int half = t >> 5;
    int l32 = t & 31;
    int n = blockIdx.x * 8 + half;
    int base = row_start[n];
    int len = deg[n] + 1;
    float ad2n = ad2[n];
    float ssum = 0.f, acc = 0.f;
    for (int i0 = 0; i0 < len; i0 += 32) {
        int clen = len - i0; if (clen > 32) clen = 32;
        int idx = i0 + l32;
        float p = 0.f; int s = 0;
        if (idx < len) {
            float4 r = rec[base + idx];
            s = __float_as_int(r.x);
            float l = as2[s] + ad2n + r.w;
            l = l > 0.f ? l : 0.2f * l;
            p = __expf(l);
        }
        ssum += p;
        spT[half][l32] = make_float2(__int_as_float(s), p);
        int i = 0;
        for (; i + 4 <= clen; i += 4) {
            float2 e0 = spT[half][i],     e1 = spT[half][i + 1];
            float2 e2 = spT[half][i + 2], e3 = spT[half][i + 3];
            int s0 = __float_as_int(e0.x), s1 = __float_as_int(e1.x);
            int s2 = __float_as_int(e2.x), s3 = __float_as_int(e3.x);
            float g0 = bf2f(h2b[(unsigned)s0 * 32u + l32]);
            float g1 = bf2f(h2b[(unsigned)s1 * 32u + l32]);
            float g2 = bf2f(h2b[(unsigned)s2 * 32u + l32]);
            float g3 = bf2f(h2b[(unsigned)s3 * 32u + l32]);
            acc = fmaf(e0.y, g0, fmaf(e1.y, g1, fmaf(e2.y, g2, fmaf(e3.y, g3, acc))));
        }
        for (; i < clen; ++i) {
            float2 e0 = spT[half][i];
            int s0 = __float_as_int(e0.x);
            acc = fmaf(e0.y, bf2f(h2b[(unsigned)s0 * 32u + l32]), acc);
        }
    }
    #pragma unroll
    for (int m = 1; m < 32; m <<= 1) ssum += __shfl_xor(ssum, m, 32);
    out[(size_t)n * 32 + l32] = acc / ssum + c2_b[l32];
}

// ---------------------------------------------------------------------------
extern "C" void kernel_launch(void* const* d_in, const int* in_sizes, int n_in,
                              void* d_out, int out_size, void* d_ws, size_t ws_size,
                              hipStream_t stream) {
    const int*   edge_index  = (const int*)  d_in[0];
    const float* edge_attr   = (const float*)d_in[1];
    const float* pol_feat    = (const float*)d_in[2];
    const int*   state_ids   = (const int*)  d_in[3];
    const int*   sector_ids  = (const int*)  d_in[4];
    const int*   industry_ids= (const int*)  d_in[5];
    const float* comp_scalar = (const float*)d_in[6];
    const float* pol_W   = (const float*)d_in[7];
    const float* pol_b   = (const float*)d_in[8];
    const float* state_E = (const float*)d_in[9];
    const float* sector_E= (const float*)d_in[10];
    const float* industry_E=(const float*)d_in[11];
    const float* comp_W  = (const float*)d_in[12];
    const float* comp_b  = (const float*)d_in[13];
    const float* comm_E  = (const float*)d_in[14];
    const float* ln_g    = (const float*)d_in[15];
    const float* ln_b    = (const float*)d_in[16];
    const float* c1_W    = (const float*)d_in[17];
    const float* c1_as   = (const float*)d_in[18];
    const float* c1_ad   = (const float*)d_in[19];
    const float* c1_eW   = (const float*)d_in[20];
    const float* c1_ae   = (const float*)d_in[21];
    const float* c1_b    = (const float*)d_in[22];
    const float* c2_W    = (const float*)d_in[23];
    const float* c2_as   = (const float*)d_in[24];
    const float* c2_ad   = (const float*)d_in[25];
    const float* c2_eW   = (const float*)d_in[26];
    const float* c2_ae   = (const float*)d_in[27];
    const float* c2_b    = (const float*)d_in[28];
    float* out = (float*)d_out;

    char* ws = (char*)d_ws;
    size_t off = 0;
    auto alloc = [&](size_t bytes) { void* p = ws + off; off += (bytes + 255) & ~(size_t)255; return p; };
    int*   deg       = (int*)  alloc(NN * 4);
    int*   ord       = (int*)  alloc((size_t)NE * 4);
    int*   row_start = (int*)  alloc(NN * 4);
    int*   bsum      = (int*)  alloc(128 * 4);
    float4* rec      = (float4*)alloc((size_t)NE2 * 16);
    unsigned short* h1b = (unsigned short*)alloc((size_t)NN * 64 * 2);
    float* as1       = (float*)alloc((size_t)NN * 4 * 4);
    float* ad1       = (float*)alloc((size_t)NN * 4 * 4);
    unsigned short* x1b = (unsigned short*)alloc((size_t)NN * 64 * 2);
    unsigned short* h2b = (unsigned short*)alloc((size_t)NN * 32 * 2);
    float* as2       = (float*)alloc(NN * 4);
    float* ad2       = (float*)alloc(NN * 4);
    (void)ws_size; (void)in_sizes; (void)n_in; (void)out_size;

    hipMemsetAsync(deg, 0, NN * 4, stream);

    k_pre<<<NPREBLK, 256, 0, stream>>>(
        edge_index, deg, ord,
        pol_feat, state_ids, sector_ids, industry_ids, comp_scalar,
        pol_W, pol_b, state_E, sector_E, industry_E, comp_W, comp_b, comm_E,
        ln_g, ln_b, c1_W, c1_as, c1_ad, h1b, as1, ad1);
    int nblk = (NN + 1023) / 1024;   // 98
    k_scan1<<<nblk, 1024, 0, stream>>>(deg, row_start, bsum);
    k_scan2<<<1, 128, 0, stream>>>(bsum, nblk);
    k_scan3<<<(NN + 255) / 256, 256, 0, stream>>>(row_start, bsum);
    k_fill<<<(NE + 255) / 256, 256, 0, stream>>>(
        edge_index, edge_attr, row_start, ord, c1_eW, c1_ae, c2_eW, c2_ae, rec);
    k_agg1<<<NN / 8, 256, 0, stream>>>(
        row_start, deg, rec, as1, ad1, h1b, c1_b, x1b);
    k_mid<<<(NN / 2) / 4, 256, 0, stream>>>(
        x1b, c2_W, c2_as, c2_ad, h2b, as2, ad2);
    k_agg2<<<NN / 8, 256, 0, stream>>>(
        row_start, deg, rec, as2, ad2, h2b, c2_b, out);
}

// Round 12
// 175.423 us; speedup vs baseline: 1.1618x; 1.0411x over previous
//
#include <hip/hip_runtime.h>
#include <math.h>

#define NPOL   1000
#define NTICK  98000
#define NCOMM  1000
#define NN     100000
#define NE     1000000
#define NFEATBLK 1563    // ceil(NN*4/256)

#define BKTSHIFT 9       // 512 nodes per bucket
#define NBKT     196     // ceil(NN/512)
#define BKTCAP   6144    // mean 5120, sigma ~71 -> +14 sigma headroom
#define KA_EPB   4096    // edges per k_bucket block
#define KA_BLOCKS 245    // ceil(NE/4096)

__device__ __forceinline__ unsigned short f2bf(float v) {
    unsigned u = __float_as_uint(v);
    u += 0x7FFFu + ((u >> 16) & 1u);          // round-to-nearest-even
    return (unsigned short)(u >> 16);
}
__device__ __forceinline__ float bf2f(unsigned short s) {
    return __uint_as_float(((unsigned)s) << 16);
}

// ---------------------------------------------------------------------------
// K_FEAT: node features -> LN -> h1 GEMV -> as1/ad1 (4 threads/node).
__global__ void __launch_bounds__(256) k_feat(
    const float* __restrict__ pol_feat, const int* __restrict__ state_ids,
    const int* __restrict__ sector_ids, const int* __restrict__ industry_ids,
    const float* __restrict__ comp_scalar,
    const float* __restrict__ pol_W, const float* __restrict__ pol_b,
    const float* __restrict__ state_E, const float* __restrict__ sector_E,
    const float* __restrict__ industry_E, const float* __restrict__ comp_W,
    const float* __restrict__ comp_b, const float* __restrict__ comm_E,
    const float* __restrict__ ln_g, const float* __restrict__ ln_b,
    const float* __restrict__ c1_W, const float* __restrict__ c1_as,
    const float* __restrict__ c1_ad,
    unsigned short* __restrict__ h1b, float* __restrict__ as1,
    float* __restrict__ ad1) {
    __shared__ float sW1[2048];
    __shared__ float sCompW[544];
    __shared__ float sPolW[224];
    __shared__ float sAs[64], sAd[64];
    __shared__ float sLg[32], sLb[32], sPb[32], sCb[32];
    int t = threadIdx.x;
    for (int i = t; i < 2048; i += 256) sW1[i] = c1_W[i];
    for (int i = t; i < 544; i += 256) sCompW[i] = comp_W[i];
    if (t < 224) sPolW[t] = pol_W[t];
    if (t < 64) { sAs[t] = c1_as[t]; sAd[t] = c1_ad[t]; }
    if (t < 32) { sLg[t] = ln_g[t]; sLb[t] = ln_b[t]; sPb[t] = pol_b[t]; sCb[t] = comp_b[t]; }
    __syncthreads();
    int tid = blockIdx.x * 256 + t;
    if (tid >= 4 * NN) return;
    int n = tid >> 2, q = tid & 3, jb = q * 8;
    float x[8];
    if (n < NPOL) {
        float f[7];
        #pragma unroll
        for (int i = 0; i < 7; ++i) f[i] = pol_feat[n * 7 + i];
        int sid = state_ids[n];
        #pragma unroll
        for (int jj = 0; jj < 8; ++jj) {
            int j = jb + jj;
            float v = sPb[j];
            #pragma unroll
            for (int i = 0; i < 7; ++i) v += f[i] * sPolW[i * 32 + j];
            v = v > 0.f ? v : 0.f;
            x[jj] = v + state_E[sid * 32 + j];
        }
    } else if (n < NPOL + NTICK) {
        int tt = n - NPOL;
        float f[17];
        int sec = sector_ids[tt], ind = industry_ids[tt];
        #pragma unroll
        for (int i = 0; i < 8; ++i) { f[i] = sector_E[sec * 8 + i]; f[8 + i] = industry_E[ind * 8 + i]; }
        f[16] = comp_scalar[tt];
        #pragma unroll
        for (int jj = 0; jj < 8; ++jj) {
            int j = jb + jj;
            float v = sCb[j];
            #pragma unroll
            for (int i = 0; i < 17; ++i) v += f[i] * sCompW[i * 32 + j];
            x[jj] = v > 0.f ? v : 0.f;
        }
    } else {
        int c = n - (NPOL + NTICK);
        float4 a = *(const float4*)&comm_E[c * 32 + jb];
        float4 b = *(const float4*)&comm_E[c * 32 + jb + 4];
        x[0] = a.x; x[1] = a.y; x[2] = a.z; x[3] = a.w;
        x[4] = b.x; x[5] = b.y; x[6] = b.z; x[7] = b.w;
    }
    float s1 = 0.f;
    #pragma unroll
    for (int jj = 0; jj < 8; ++jj) s1 += x[jj];
    s1 += __shfl_xor(s1, 1); s1 += __shfl_xor(s1, 2);
    float mu = s1 * (1.f / 32.f);
    float s2 = 0.f;
    #pragma unroll
    for (int jj = 0; jj < 8; ++jj) { float dd = x[jj] - mu; s2 += dd * dd; }
    s2 += __shfl_xor(s2, 1); s2 += __shfl_xor(s2, 2);
    float inv = rsqrtf(s2 * (1.f / 32.f) + 1e-5f);
    #pragma unroll
    for (int jj = 0; jj < 8; ++jj) x[jj] = (x[jj] - mu) * inv * sLg[jb + jj] + sLb[jb + jj];
    float4 acc0 = {0,0,0,0}, acc1 = {0,0,0,0}, acc2 = {0,0,0,0}, acc3 = {0,0,0,0};
    int qb = (t & 63) & ~3;
    int jc = q * 16;
    #pragma unroll
    for (int p = 0; p < 4; ++p) {
        #pragma unroll
        for (int jj = 0; jj < 8; ++jj) {
            float xs = __shfl(x[jj], qb + p, 64);
            const float4* wr = (const float4*)&sW1[(p * 8 + jj) * 64 + jc];
            float4 w0 = wr[0], w1 = wr[1], w2 = wr[2], w3 = wr[3];
            acc0.x = fmaf(xs, w0.x, acc0.x); acc0.y = fmaf(xs, w0.y, acc0.y);
            acc0.z = fmaf(xs, w0.z, acc0.z); acc0.w = fmaf(xs, w0.w, acc0.w);
            acc1.x = fmaf(xs, w1.x, acc1.x); acc1.y = fmaf(xs, w1.y, acc1.y);
            acc1.z = fmaf(xs, w1.z, acc1.z); acc1.w = fmaf(xs, w1.w, acc1.w);
            acc2.x = fmaf(xs, w2.x, acc2.x); acc2.y = fmaf(xs, w2.y, acc2.y);
            acc2.z = fmaf(xs, w2.z, acc2.z); acc2.w = fmaf(xs, w2.w, acc2.w);
            acc3.x = fmaf(xs, w3.x, acc3.x); acc3.y = fmaf(xs, w3.y, acc3.y);
            acc3.z = fmaf(xs, w3.z, acc3.z); acc3.w = fmaf(xs, w3.w, acc3.w);
        }
    }
    const float4* asv = (const float4*)sAs;
    const float4* adv = (const float4*)sAd;
    float4 a0 = asv[q * 4], a1 = asv[q * 4 + 1], a2 = asv[q * 4 + 2], a3 = asv[q * 4 + 3];
    float4 b0 = adv[q * 4], b1v = adv[q * 4 + 1], b2v = adv[q * 4 + 2], b3 = adv[q * 4 + 3];
    float av = acc0.x * a0.x + acc0.y * a0.y + acc0.z * a0.z + acc0.w * a0.w
             + acc1.x * a1.x + acc1.y * a1.y + acc1.z * a1.z + acc1.w * a1.w
             + acc2.x * a2.x + acc2.y * a2.y + acc2.z * a2.z + acc2.w * a2.w
             + acc3.x * a3.x + acc3.y * a3.y + acc3.z * a3.z + acc3.w * a3.w;
    float dv = acc0.x * b0.x + acc0.y * b0.y + acc0.z * b0.z + acc0.w * b0.w
             + acc1.x * b1v.x + acc1.y * b1v.y + acc1.z * b1v.z + acc1.w * b1v.w
             + acc2.x * b2v.x + acc2.y * b2v.y + acc2.z * b2v.z + acc2.w * b2v.w
             + acc3.x * b3.x + acc3.y * b3.y + acc3.z * b3.z + acc3.w * b3.w;
    as1[tid] = av;
    ad1[tid] = dv;
    uint4 w1o, w2o;
    w1o.x = (unsigned)f2bf(acc0.x) | ((unsigned)f2bf(acc0.y) << 16);
    w1o.y = (unsigned)f2bf(acc0.z) | ((unsigned)f2bf(acc0.w) << 16);
    w1o.z = (unsigned)f2bf(acc1.x) | ((unsigned)f2bf(acc1.y) << 16);
    w1o.w = (unsigned)f2bf(acc1.z) | ((unsigned)f2bf(acc1.w) << 16);
    w2o.x = (unsigned)f2bf(acc2.x) | ((unsigned)f2bf(acc2.y) << 16);
    w2o.y = (unsigned)f2bf(acc2.z) | ((unsigned)f2bf(acc2.w) << 16);
    w2o.z = (unsigned)f2bf(acc3.x) | ((unsigned)f2bf(acc3.y) << 16);
    w2o.w = (unsigned)f2bf(acc3.z) | ((unsigned)f2bf(acc3.w) << 16);
    unsigned short* hp = h1b + (unsigned)n * 64u + (unsigned)jc;
    *(uint4*)hp = w1o;
    *(uint4*)(hp + 8) = w2o;
}

// ---------------------------------------------------------------------------
// K_BUCKET: 4 edges/thread. Computes the full 16B record in-kernel and
// scatters it into per-bucket (512-node) arrays. Ranks via LDS atomics;
// only ~48K global atomics on 196 line-padded counters (vs 1M memory-side
// atomics before — the R11 wall).
__global__ void __launch_bounds__(1024) k_bucket(
    const int* __restrict__ ei, const float* __restrict__ edge_attr,
    const float* __restrict__ c1_eW, const float* __restrict__ c1_ae,
    const float* __restrict__ c2_eW, const float* __restrict__ c2_ae,
    int* __restrict__ bucket_cnt, float4* __restrict__ bucketbuf) {
    __shared__ float we1s[20];
    __shared__ float we2s[5];
    __shared__ int hcnt[NBKT];
    __shared__ int hbase[NBKT];
    int t = threadIdx.x;
    if (t < 20) {
        int d = t >> 2, h = t & 3;
        float s = 0.f;
        for (int f = 0; f < 16; ++f) s += c1_eW[d * 64 + h * 16 + f] * c1_ae[h * 16 + f];
        we1s[t] = s;
    } else if (t >= 32 && t < 37) {
        int d = t - 32;
        float s = 0.f;
        for (int f = 0; f < 32; ++f) s += c2_eW[d * 32 + f] * c2_ae[f];
        we2s[d] = s;
    }
    if (t < NBKT) hcnt[t] = 0;
    __syncthreads();
    int e0 = blockIdx.x * KA_EPB + t;
    int bk[4], rk[4];
    float4 rec[4];
    #pragma unroll
    for (int k = 0; k < 4; ++k) {
        int e = e0 + k * 1024;
        bk[k] = -1;
        if (e < NE) {
            int s = ei[e];
            int d = ei[NE + e];
            int bkt = d >> BKTSHIFT;
            int dl = d & ((1 << BKTSHIFT) - 1);
            float a[5];
            #pragma unroll
            for (int kk = 0; kk < 5; ++kk) a[kk] = edge_attr[e * 5 + kk];
            float v0 = 0.f, v1 = 0.f, v2 = 0.f, v3 = 0.f, v4 = 0.f;
            #pragma unroll
            for (int kk = 0; kk < 5; ++kk) {
                v0 += a[kk] * we1s[kk * 4 + 0];
                v1 += a[kk] * we1s[kk * 4 + 1];
                v2 += a[kk] * we1s[kk * 4 + 2];
                v3 += a[kk] * we1s[kk * 4 + 3];
                v4 += a[kk] * we2s[kk];
            }
            unsigned u01 = (unsigned)f2bf(v0) | ((unsigned)f2bf(v1) << 16);
            unsigned u23 = (unsigned)f2bf(v2) | ((unsigned)f2bf(v3) << 16);
            unsigned pk = (unsigned)s | ((unsigned)dl << 17);   // src<2^17, dl<512
            rec[k] = make_float4(__uint_as_float(pk), __uint_as_float(u01),
                                 __uint_as_float(u23), v4);
            bk[k] = bkt;
            rk[k] = atomicAdd(&hcnt[bkt], 1);
        }
    }
    __syncthreads();
    if (t < NBKT && hcnt[t] > 0) hbase[t] = atomicAdd(&bucket_cnt[t * 16], hcnt[t]);
    __syncthreads();
    #pragma unroll
    for (int k = 0; k < 4; ++k) {
        if (bk[k] >= 0) {
            int pos = hbase[bk[k]] + rk[k];
            if (pos < BKTCAP)
                bucketbuf[(size_t)bk[k] * BKTCAP + pos] = rec[k];
        }
    }
}

// ---------------------------------------------------------------------------
// K_SORTFILL: one block per bucket. LDS histogram over the bucket's 512
// local nodes -> deg/erow written coalesced (no global scan kernels);
// records scattered to final CSR slots — all within an ~82KB region, so L2
// absorbs the writes into full lines (kills the old 4x write amplification).
__global__ void __launch_bounds__(1024) k_sortfill(
    const int* __restrict__ bucket_cnt, const float4* __restrict__ bucketbuf,
    float4* __restrict__ rec2, int* __restrict__ deg, int* __restrict__ erow) {
    __shared__ int pref[256];
    __shared__ int hist[512];
    __shared__ int hoff[512];
    int t = threadIdx.x;
    int b = blockIdx.x;
    if (t < 256) pref[t] = (t < NBKT) ? bucket_cnt[t * 16] : 0;
    if (t < 512) hist[t] = 0;
    __syncthreads();
    for (int off = 1; off < 256; off <<= 1) {
        int v = 0;
        if (t < 256 && t >= off) v = pref[t - off];
        __syncthreads();
        if (t < 256) pref[t] += v;
        __syncthreads();
    }
    int count = bucket_cnt[b * 16];
    if (count > BKTCAP) count = BKTCAP;
    int region = (b == 0) ? 0 : pref[b - 1];
    // pass 1: rank within local node
    float4 rv[6];
    int dlv[6], rrv[6];
    #pragma unroll
    for (int k = 0; k < 6; ++k) {
        int i = k * 1024 + t;
        dlv[k] = -1;
        if (i < count) {
            float4 p = bucketbuf[(size_t)b * BKTCAP + i];
            int dl = (int)(__float_as_uint(p.x) >> 17);
            p.x = __uint_as_float(__float_as_uint(p.x) & 0x1FFFFu);  // keep src only
            rv[k] = p;
            dlv[k] = dl;
            rrv[k] = atomicAdd(&hist[dl], 1);
        }
    }
    __syncthreads();
    if (t < 512) hoff[t] = hist[t];
    __syncthreads();
    for (int off = 1; off < 512; off <<= 1) {
        int v = 0;
        if (t < 512 && t >= off) v = hoff[t - off];
        __syncthreads();
        if (t < 512) hoff[t] += v;
        __syncthreads();
    }
    // pass 2: scatter to final CSR slots (hoff inclusive -> exclusive = hoff-hist)
    #pragma unroll
    for (int k = 0; k < 6; ++k) {
        if (dlv[k] >= 0) {
            int pos = region + hoff[dlv[k]] - hist[dlv[k]] + rrv[k];
            rec2[pos] = rv[k];
        }
    }
    int n = (b << BKTSHIFT) + t;
    if (t < 512 && n < NN) {
        deg[n] = hist[t];
        erow[n] = region + hoff[t] - hist[t];
    }
}

// ---------------------------------------------------------------------------
// K6: GAT layer 1. One wave = 2 nodes; lane owns dims {2j,2j+1}.
__global__ void __launch_bounds__(256) k_agg1(
    const int* __restrict__ erow, const int* __restrict__ deg,
    const float4* __restrict__ rec2,
    const float* __restrict__ as1, const float* __restrict__ ad1,
    const unsigned short* __restrict__ h1b, const float* __restrict__ c1_b,
    unsigned short* __restrict__ x1b, float* __restrict__ selfae2) {
    __shared__ float pT[4][2][32][4];
    __shared__ int   srcT[4][2][32];
    int wid = threadIdx.x >> 6;
    int lane = threadIdx.x & 63;
    int half = lane >> 5;
    int j = lane & 31;
    int h = j >> 3;
    int n = blockIdx.x * 8 + wid * 2 + half;
    int base = erow[n];
    int dg   = deg[n];
    const float4* as1v4 = (const float4*)as1;
    const float4* ad1v4 = (const float4*)ad1;
    float4 adv = ad1v4[n];
    float4 asv = as1v4[n];
    unsigned uself = *(const unsigned*)(h1b + (unsigned)n * 64u + 2u * (unsigned)j);

    float ssum = 0.f, acc0 = 0.f, acc1 = 0.f;
    float aes0 = 0.f, aes1 = 0.f, aes2 = 0.f, aes3 = 0.f, ae2sum = 0.f;

    for (int i0 = 0; i0 < dg; i0 += 32) {
        int clen = dg - i0; if (clen > 32) clen = 32;
        int idx = i0 + j;
        if (idx < dg) {
            float4 r = rec2[base + idx];
            int s = __float_as_int(r.x);
            unsigned u01 = __float_as_uint(r.y), u23 = __float_as_uint(r.z);
            float ae0  = bf2f((unsigned short)u01);
            float ae1v = bf2f((unsigned short)(u01 >> 16));
            float ae2v = bf2f((unsigned short)u23);
            float ae3v = bf2f((unsigned short)(u23 >> 16));
            float4 av = as1v4[s];
            float l0 = av.x + adv.x + ae0;  l0 = l0 > 0.f ? l0 : 0.2f * l0;
            float l1 = av.y + adv.y + ae1v; l1 = l1 > 0.f ? l1 : 0.2f * l1;
            float l2 = av.z + adv.z + ae2v; l2 = l2 > 0.f ? l2 : 0.2f * l2;
            float l3 = av.w + adv.w + ae3v; l3 = l3 > 0.f ? l3 : 0.2f * l3;
            float4 q = make_float4(__expf(l0), __expf(l1), __expf(l2), __expf(l3));
            *(float4*)&pT[wid][half][j][0] = q;
            srcT[wid][half][j] = s;
            aes0 += ae0; aes1 += ae1v; aes2 += ae2v; aes3 += ae3v;
            ae2sum += r.w;
        }
        int i = 0;
        for (; i + 4 <= clen; i += 4) {
            int s0 = srcT[wid][half][i],     s1 = srcT[wid][half][i + 1];
            int s2 = srcT[wid][half][i + 2], s3 = srcT[wid][half][i + 3];
            float q0 = pT[wid][half][i][h],     q1 = pT[wid][half][i + 1][h];
            float q2 = pT[wid][half][i + 2][h], q3 = pT[wid][half][i + 3][h];
            unsigned g0 = *(const unsigned*)(h1b + (unsigned)s0 * 64u + 2u * (unsigned)j);
            unsigned g1 = *(const unsigned*)(h1b + (unsigned)s1 * 64u + 2u * (unsigned)j);
            unsigned g2 = *(const unsigned*)(h1b + (unsigned)s2 * 64u + 2u * (unsigned)j);
            unsigned g3 = *(const unsigned*)(h1b + (unsigned)s3 * 64u + 2u * (unsigned)j);
            ssum += (q0 + q1) + (q2 + q3);
            acc0 = fmaf(q0, bf2f((unsigned short)g0),
                   fmaf(q1, bf2f((unsigned short)g1),
                   fmaf(q2, bf2f((unsigned short)g2),
                   fmaf(q3, bf2f((unsigned short)g3), acc0))));
            acc1 = fmaf(q0, bf2f((unsigned short)(g0 >> 16)),
                   fmaf(q1, bf2f((unsigned short)(g1 >> 16)),
                   fmaf(q2, bf2f((unsigned short)(g2 >> 16)),
                   fmaf(q3, bf2f((unsigned short)(g3 >> 16)), acc1))));
        }
        for (; i < clen; ++i) {
            int s0 = srcT[wid][half][i];
            float q0 = pT[wid][half][i][h];
            unsigned g0 = *(const unsigned*)(h1b + (unsigned)s0 * 64u + 2u * (unsigned)j);
            ssum += q0;
            acc0 = fmaf(q0, bf2f((unsigned short)g0), acc0);
            acc1 = fmaf(q0, bf2f((unsigned short)(g0 >> 16)), acc1);
        }
    }
    #pragma unroll
    for (int m = 1; m < 32; m <<= 1) {
        aes0 += __shfl_xor(aes0, m);
        aes1 += __shfl_xor(aes1, m);
        aes2 += __shfl_xor(aes2, m);
        aes3 += __shfl_xor(aes3, m);
        ae2sum += __shfl_xor(ae2sum, m);
    }
    float invd = 1.f / fmaxf((float)dg, 1.f);
    float aesh = (h == 0) ? aes0 : (h == 1) ? aes1 : (h == 2) ? aes2 : aes3;
    float adh  = (h == 0) ? adv.x : (h == 1) ? adv.y : (h == 2) ? adv.z : adv.w;
    float ash  = (h == 0) ? asv.x : (h == 1) ? asv.y : (h == 2) ? asv.z : asv.w;
    float ls = ash + adh + aesh * invd;
    ls = ls > 0.f ? ls : 0.2f * ls;
    float ps = __expf(ls);
    ssum += ps;
    acc0 = fmaf(ps, bf2f((unsigned short)uself), acc0);
    acc1 = fmaf(ps, bf2f((unsigned short)(uself >> 16)), acc1);
    if (lane == 0) selfae2[n] = ae2sum * invd;
    if (lane == 32) selfae2[n] = ae2sum * invd;   // half=1's node
    float inv_s = 1.f / ssum;
    float x0 = acc0 * inv_s + c1_b[2 * j];
    float x1 = acc1 * inv_s + c1_b[2 * j + 1];
    x0 = (x0 > 0.f) ? x0 : (__expf(x0) - 1.f);   // ELU
    x1 = (x1 > 0.f) ? x1 : (__expf(x1) - 1.f);
    unsigned w = (unsigned)f2bf(x0) | ((unsigned)f2bf(x1) << 16);
    *(unsigned*)(x1b + (unsigned)n * 64u + 2u * (unsigned)j) = w;
}

// ---------------------------------------------------------------------------
// K6.5: wave-cooperative GEMV h2 = x1 @ c2_W (64->32) + as2/ad2 scalars.
__global__ void __launch_bounds__(256) k_mid(
    const unsigned short* __restrict__ x1b, const float* __restrict__ c2_W,
    const float* __restrict__ c2_as, const float* __restrict__ c2_ad,
    unsigned short* __restrict__ h2b, float* __restrict__ as2,
    float* __restrict__ ad2) {
    int wave = (blockIdx.x * 256 + threadIdx.x) >> 6;   // 50000 waves
    int lane = threadIdx.x & 63;
    int half = lane >> 5, j = lane & 31;
    int n = wave * 2 + half;
    unsigned u = *(const unsigned*)(x1b + (unsigned)n * 64u + j * 2u);
    float acc = 0.f;
    #pragma unroll
    for (int t = 0; t < 32; ++t) {
        unsigned xu = (unsigned)__shfl((int)u, half * 32 + t, 64);
        float x0 = bf2f((unsigned short)xu);
        float x1 = bf2f((unsigned short)(xu >> 16));
        acc = fmaf(x0, c2_W[(2 * t) * 32 + j], acc);
        acc = fmaf(x1, c2_W[(2 * t + 1) * 32 + j], acc);
    }
    float a = acc * c2_as[j], b = acc * c2_ad[j];
    #pragma unroll
    for (int m = 16; m > 0; m >>= 1) {
        a += __shfl_xor(a, m, 64);
        b += __shfl_xor(b, m, 64);
    }
    if (j == 0) { as2[n] = a; ad2[n] = b; }
    h2b[(unsigned)n * 32u + j] = f2bf(acc);
}

// ---------------------------------------------------------------------------
// K7: GAT layer 2, one 32-lane group per dst; self via selfae2.
__global__ void __launch_bounds__(256) k_agg2(
    const int* __restrict__ erow, const int* __restrict__ deg,
    const float4* __restrict__ rec2, const float* __restrict__ as2,
    const float* __restrict__ ad2, const float* __restrict__ selfae2,
    const unsigned short* __restrict__ h2b, const float* __restrict__ c2_b,
    float* __restrict__ out) {
    __shared__ float2 spT[8][32];
    int t = threadIdx.x;
    int half = t >> 5;
    int l32 = t & 31;
    int n = blockIdx.x * 8 + half;
    int base = erow[n];
    int dg = deg[n];
    float ad2n = ad2[n];
    float ssum = 0.f, acc = 0.f;
    for (int i0 = 0; i0 < dg; i0 += 32) {
        int clen = dg - i0; if (clen > 32) clen = 32;
        int idx = i0 + l32;
        float p = 0.f; int s = 0;
        if (idx < dg) {
            float4 r = rec2[base + idx];
            s = __float_as_int(r.x);
            float l = as2[s] + ad2n + r.w;
            l = l > 0.f ? l : 0.2f * l;
            p = __expf(l);
        }
        ssum += p;
        spT[half][l32] = make_float2(__int_as_float(s), p);
        int i = 0;
        for (; i + 4 <= clen; i += 4) {
            float2 e0 = spT[half][i],     e1 = spT[half][i + 1];
            float2 e2 = spT[half][i + 2], e3 = spT[half][i + 3];
            int s0 = __float_as_int(e0.x), s1 = __float_as_int(e1.x);
            int s2 = __float_as_int(e2.x), s3 = __float_as_int(e3.x);
            float g0 = bf2f(h2b[(unsigned)s0 * 32u + l32]);
            float g1 = bf2f(h2b[(unsigned)s1 * 32u + l32]);
            float g2 = bf2f(h2b[(unsigned)s2 * 32u + l32]);
            float g3 = bf2f(h2b[(unsigned)s3 * 32u + l32]);
            acc = fmaf(e0.y, g0, fmaf(e1.y, g1, fmaf(e2.y, g2, fmaf(e3.y, g3, acc))));
        }
        for (; i < clen; ++i) {
            float2 e0 = spT[half][i];
            int s0 = __float_as_int(e0.x);
            acc = fmaf(e0.y, bf2f(h2b[(unsigned)s0 * 32u + l32]), acc);
        }
    }
    #pragma unroll
    for (int m = 1; m < 32; m <<= 1) ssum += __shfl_xor(ssum, m, 32);
    // self-loop
    float ls = as2[n] + ad2n + selfae2[n];
    ls = ls > 0.f ? ls : 0.2f * ls;
    float ps = __expf(ls);
    ssum += ps;
    acc = fmaf(ps, bf2f(h2b[(unsigned)n * 32u + l32]), acc);
    out[(size_t)n * 32 + l32] = acc / ssum + c2_b[l32];
}

// ---------------------------------------------------------------------------
extern "C" void kernel_launch(void* const* d_in, const int* in_sizes, int n_in,
                              void* d_out, int out_size, void* d_ws, size_t ws_size,
                              hipStream_t stream) {
    const int*   edge_index  = (const int*)  d_in[0];
    const float* edge_attr   = (const float*)d_in[1];
    const float* pol_feat    = (const float*)d_in[2];
    const int*   state_ids   = (const int*)  d_in[3];
    const int*   sector_ids  = (const int*)  d_in[4];
    const int*   industry_ids= (const int*)  d_in[5];
    const float* comp_scalar = (const float*)d_in[6];
    const float* pol_W   = (const float*)d_in[7];
    const float* pol_b   = (const float*)d_in[8];
    const float* state_E = (const float*)d_in[9];
    const float* sector_E= (const float*)d_in[10];
    const float* industry_E=(const float*)d_in[11];
    const float* comp_W  = (const float*)d_in[12];
    const float* comp_b  = (const float*)d_in[13];
    const float* comm_E  = (const float*)d_in[14];
    const float* ln_g    = (const float*)d_in[15];
    const float* ln_b    = (const float*)d_in[16];
    const float* c1_W    = (const float*)d_in[17];
    const float* c1_as   = (const float*)d_in[18];
    const float* c1_ad   = (const float*)d_in[19];
    const float* c1_eW   = (const float*)d_in[20];
    const float* c1_ae   = (const float*)d_in[21];
    const float* c1_b    = (const float*)d_in[22];
    const float* c2_W    = (const float*)d_in[23];
    const float* c2_as   = (const float*)d_in[24];
    const float* c2_ad   = (const float*)d_in[25];
    const float* c2_eW   = (const float*)d_in[26];
    const float* c2_ae   = (const float*)d_in[27];
    const float* c2_b    = (const float*)d_in[28];
    float* out = (float*)d_out;

    char* ws = (char*)d_ws;
    size_t off = 0;
    auto alloc = [&](size_t bytes) { void* p = ws + off; off += (bytes + 255) & ~(size_t)255; return p; };
    int*    bucket_cnt = (int*)   alloc((size_t)NBKT * 16 * 4);  // 64B-strided counters
    float4* bucketbuf  = (float4*)alloc((size_t)NBKT * BKTCAP * 16);
    float4* rec2       = (float4*)alloc((size_t)NE * 16);
    int*    deg        = (int*)   alloc(NN * 4);
    int*    erow       = (int*)   alloc(NN * 4);
    float*  selfae2    = (float*) alloc(NN * 4);
    unsigned short* h1b = (unsigned short*)alloc((size_t)NN * 64 * 2);
    float* as1       = (float*)alloc((size_t)NN * 4 * 4);
    float* ad1       = (float*)alloc((size_t)NN * 4 * 4);
    unsigned short* x1b = (unsigned short*)alloc((size_t)NN * 64 * 2);
    unsigned short* h2b = (unsigned short*)alloc((size_t)NN * 32 * 2);
    float* as2       = (float*)alloc(NN * 4);
    float* ad2       = (float*)alloc(NN * 4);
    (void)ws_size; (void)in_sizes; (void)n_in; (void)out_size;

    hipMemsetAsync(bucket_cnt, 0, (size_t)NBKT * 16 * 4, stream);

    k_feat<<<NFEATBLK, 256, 0, stream>>>(
        pol_feat, state_ids, sector_ids, industry_ids, comp_scalar,
        pol_W, pol_b, state_E, sector_E, industry_E, comp_W, comp_b, comm_E,
        ln_g, ln_b, c1_W, c1_as, c1_ad, h1b, as1, ad1);
    k_bucket<<<KA_BLOCKS, 1024, 0, stream>>>(
        edge_index, edge_attr, c1_eW, c1_ae, c2_eW, c2_ae, bucket_cnt, bucketbuf);
    k_sortfill<<<NBKT, 1024, 0, stream>>>(
        bucket_cnt, bucketbuf, rec2, deg, erow);
    k_agg1<<<NN / 8, 256, 0, stream>>>(
        erow, deg, rec2, as1, ad1, h1b, c1_b, x1b, selfae2);
    k_mid<<<(NN / 2) / 4, 256, 0, stream>>>(
        x1b, c2_W, c2_as, c2_ad, h2b, as2, ad2);
    k_agg2<<<NN / 8, 256, 0, stream>>>(
        erow, deg, rec2, as2, ad2, selfae2, h2b, c2_b, out);
}

// Round 13
// 170.852 us; speedup vs baseline: 1.1929x; 1.0268x over previous
//
#include <hip/hip_runtime.h>
#include <math.h>

#define NPOL   1000
#define NTICK  98000
#define NCOMM  1000
#define NN     100000
#define NE     1000000
#define NFEATBLK 1563    // ceil(NN*4/256)

#define BKTSHIFT 9       // 512 nodes per bucket
#define NBKT     196     // ceil(NN/512)
#define BKTCAP   6144    // mean 5120, sigma ~71 -> +14 sigma headroom
#define KA_EPB   4096    // edges per k_bucket block
#define KA_BLOCKS 245    // ceil(NE/4096)

__device__ __forceinline__ unsigned short f2bf(float v) {
    unsigned u = __float_as_uint(v);
    u += 0x7FFFu + ((u >> 16) & 1u);          // round-to-nearest-even
    return (unsigned short)(u >> 16);
}
__device__ __forceinline__ float bf2f(unsigned short s) {
    return __uint_as_float(((unsigned)s) << 16);
}

// ---------------------------------------------------------------------------
// K_FEAT: node features -> LN -> h1 GEMV -> as1/ad1 (4 threads/node).
// Block 0 also zeroes bucket_cnt (replaces hipMemsetAsync: the graph-captured
// memset dispatch cost a fixed ~41us/replay — R12 profile).
__global__ void __launch_bounds__(256) k_feat(
    const float* __restrict__ pol_feat, const int* __restrict__ state_ids,
    const int* __restrict__ sector_ids, const int* __restrict__ industry_ids,
    const float* __restrict__ comp_scalar,
    const float* __restrict__ pol_W, const float* __restrict__ pol_b,
    const float* __restrict__ state_E, const float* __restrict__ sector_E,
    const float* __restrict__ industry_E, const float* __restrict__ comp_W,
    const float* __restrict__ comp_b, const float* __restrict__ comm_E,
    const float* __restrict__ ln_g, const float* __restrict__ ln_b,
    const float* __restrict__ c1_W, const float* __restrict__ c1_as,
    const float* __restrict__ c1_ad,
    unsigned short* __restrict__ h1b, float* __restrict__ as1,
    float* __restrict__ ad1, int* __restrict__ bucket_cnt) {
    __shared__ float sW1[2048];
    __shared__ float sCompW[544];
    __shared__ float sPolW[224];
    __shared__ float sAs[64], sAd[64];
    __shared__ float sLg[32], sLb[32], sPb[32], sCb[32];
    int t = threadIdx.x;
    if (blockIdx.x == 0) {
        for (int i = t; i < NBKT * 16; i += 256) bucket_cnt[i] = 0;
    }
    for (int i = t; i < 2048; i += 256) sW1[i] = c1_W[i];
    for (int i = t; i < 544; i += 256) sCompW[i] = comp_W[i];
    if (t < 224) sPolW[t] = pol_W[t];
    if (t < 64) { sAs[t] = c1_as[t]; sAd[t] = c1_ad[t]; }
    if (t < 32) { sLg[t] = ln_g[t]; sLb[t] = ln_b[t]; sPb[t] = pol_b[t]; sCb[t] = comp_b[t]; }
    __syncthreads();
    int tid = blockIdx.x * 256 + t;
    if (tid >= 4 * NN) return;
    int n = tid >> 2, q = tid & 3, jb = q * 8;
    float x[8];
    if (n < NPOL) {
        float f[7];
        #pragma unroll
        for (int i = 0; i < 7; ++i) f[i] = pol_feat[n * 7 + i];
        int sid = state_ids[n];
        #pragma unroll
        for (int jj = 0; jj < 8; ++jj) {
            int j = jb + jj;
            float v = sPb[j];
            #pragma unroll
            for (int i = 0; i < 7; ++i) v += f[i] * sPolW[i * 32 + j];
            v = v > 0.f ? v : 0.f;
            x[jj] = v + state_E[sid * 32 + j];
        }
    } else if (n < NPOL + NTICK) {
        int tt = n - NPOL;
        float f[17];
        int sec = sector_ids[tt], ind = industry_ids[tt];
        #pragma unroll
        for (int i = 0; i < 8; ++i) { f[i] = sector_E[sec * 8 + i]; f[8 + i] = industry_E[ind * 8 + i]; }
        f[16] = comp_scalar[tt];
        #pragma unroll
        for (int jj = 0; jj < 8; ++jj) {
            int j = jb + jj;
            float v = sCb[j];
            #pragma unroll
            for (int i = 0; i < 17; ++i) v += f[i] * sCompW[i * 32 + j];
            x[jj] = v > 0.f ? v : 0.f;
        }
    } else {
        int c = n - (NPOL + NTICK);
        float4 a = *(const float4*)&comm_E[c * 32 + jb];
        float4 b = *(const float4*)&comm_E[c * 32 + jb + 4];
        x[0] = a.x; x[1] = a.y; x[2] = a.z; x[3] = a.w;
        x[4] = b.x; x[5] = b.y; x[6] = b.z; x[7] = b.w;
    }
    float s1 = 0.f;
    #pragma unroll
    for (int jj = 0; jj < 8; ++jj) s1 += x[jj];
    s1 += __shfl_xor(s1, 1); s1 += __shfl_xor(s1, 2);
    float mu = s1 * (1.f / 32.f);
    float s2 = 0.f;
    #pragma unroll
    for (int jj = 0; jj < 8; ++jj) { float dd = x[jj] - mu; s2 += dd * dd; }
    s2 += __shfl_xor(s2, 1); s2 += __shfl_xor(s2, 2);
    float inv = rsqrtf(s2 * (1.f / 32.f) + 1e-5f);
    #pragma unroll
    for (int jj = 0; jj < 8; ++jj) x[jj] = (x[jj] - mu) * inv * sLg[jb + jj] + sLb[jb + jj];
    float4 acc0 = {0,0,0,0}, acc1 = {0,0,0,0}, acc2 = {0,0,0,0}, acc3 = {0,0,0,0};
    int qb = (t & 63) & ~3;
    int jc = q * 16;
    #pragma unroll
    for (int p = 0; p < 4; ++p) {
        #pragma unroll
        for (int jj = 0; jj < 8; ++jj) {
            float xs = __shfl(x[jj], qb + p, 64);
            const float4* wr = (const float4*)&sW1[(p * 8 + jj) * 64 + jc];
            float4 w0 = wr[0], w1 = wr[1], w2 = wr[2], w3 = wr[3];
            acc0.x = fmaf(xs, w0.x, acc0.x); acc0.y = fmaf(xs, w0.y, acc0.y);
            acc0.z = fmaf(xs, w0.z, acc0.z); acc0.w = fmaf(xs, w0.w, acc0.w);
            acc1.x = fmaf(xs, w1.x, acc1.x); acc1.y = fmaf(xs, w1.y, acc1.y);
            acc1.z = fmaf(xs, w1.z, acc1.z); acc1.w = fmaf(xs, w1.w, acc1.w);
            acc2.x = fmaf(xs, w2.x, acc2.x); acc2.y = fmaf(xs, w2.y, acc2.y);
            acc2.z = fmaf(xs, w2.z, acc2.z); acc2.w = fmaf(xs, w2.w, acc2.w);
            acc3.x = fmaf(xs, w3.x, acc3.x); acc3.y = fmaf(xs, w3.y, acc3.y);
            acc3.z = fmaf(xs, w3.z, acc3.z); acc3.w = fmaf(xs, w3.w, acc3.w);
        }
    }
    const float4* asv = (const float4*)sAs;
    const float4* adv = (const float4*)sAd;
    float4 a0 = asv[q * 4], a1 = asv[q * 4 + 1], a2 = asv[q * 4 + 2], a3 = asv[q * 4 + 3];
    float4 b0 = adv[q * 4], b1v = adv[q * 4 + 1], b2v = adv[q * 4 + 2], b3 = adv[q * 4 + 3];
    float av = acc0.x * a0.x + acc0.y * a0.y + acc0.z * a0.z + acc0.w * a0.w
             + acc1.x * a1.x + acc1.y * a1.y + acc1.z * a1.z + acc1.w * a1.w
             + acc2.x * a2.x + acc2.y * a2.y + acc2.z * a2.z + acc2.w * a2.w
             + acc3.x * a3.x + acc3.y * a3.y + acc3.z * a3.z + acc3.w * a3.w;
    float dv = acc0.x * b0.x + acc0.y * b0.y + acc0.z * b0.z + acc0.w * b0.w
             + acc1.x * b1v.x + acc1.y * b1v.y + acc1.z * b1v.z + acc1.w * b1v.w
             + acc2.x * b2v.x + acc2.y * b2v.y + acc2.z * b2v.z + acc2.w * b2v.w
             + acc3.x * b3.x + acc3.y * b3.y + acc3.z * b3.z + acc3.w * b3.w;
    as1[tid] = av;
    ad1[tid] = dv;
    uint4 w1o, w2o;
    w1o.x = (unsigned)f2bf(acc0.x) | ((unsigned)f2bf(acc0.y) << 16);
    w1o.y = (unsigned)f2bf(acc0.z) | ((unsigned)f2bf(acc0.w) << 16);
    w1o.z = (unsigned)f2bf(acc1.x) | ((unsigned)f2bf(acc1.y) << 16);
    w1o.w = (unsigned)f2bf(acc1.z) | ((unsigned)f2bf(acc1.w) << 16);
    w2o.x = (unsigned)f2bf(acc2.x) | ((unsigned)f2bf(acc2.y) << 16);
    w2o.y = (unsigned)f2bf(acc2.z) | ((unsigned)f2bf(acc2.w) << 16);
    w2o.z = (unsigned)f2bf(acc3.x) | ((unsigned)f2bf(acc3.y) << 16);
    w2o.w = (unsigned)f2bf(acc3.z) | ((unsigned)f2bf(acc3.w) << 16);
    unsigned short* hp = h1b + (unsigned)n * 64u + (unsigned)jc;
    *(uint4*)hp = w1o;
    *(uint4*)(hp + 8) = w2o;
}

// ---------------------------------------------------------------------------
// K_BUCKET: 4 edges/thread. Full 16B record computed in-kernel, scattered to
// per-bucket (512-node) arrays. Ranks via LDS atomics; ~48K global atomics.
__global__ void __launch_bounds__(1024) k_bucket(
    const int* __restrict__ ei, const float* __restrict__ edge_attr,
    const float* __restrict__ c1_eW, const float* __restrict__ c1_ae,
    const float* __restrict__ c2_eW, const float* __restrict__ c2_ae,
    int* __restrict__ bucket_cnt, float4* __restrict__ bucketbuf) {
    __shared__ float we1s[20];
    __shared__ float we2s[5];
    __shared__ int hcnt[NBKT];
    __shared__ int hbase[NBKT];
    int t = threadIdx.x;
    if (t < 20) {
        int d = t >> 2, h = t & 3;
        float s = 0.f;
        for (int f = 0; f < 16; ++f) s += c1_eW[d * 64 + h * 16 + f] * c1_ae[h * 16 + f];
        we1s[t] = s;
    } else if (t >= 32 && t < 37) {
        int d = t - 32;
        float s = 0.f;
        for (int f = 0; f < 32; ++f) s += c2_eW[d * 32 + f] * c2_ae[f];
        we2s[d] = s;
    }
    if (t < NBKT) hcnt[t] = 0;
    __syncthreads();
    int e0 = blockIdx.x * KA_EPB + t;
    int bk[4], rk[4];
    float4 rec[4];
    #pragma unroll
    for (int k = 0; k < 4; ++k) {
        int e = e0 + k * 1024;
        bk[k] = -1;
        if (e < NE) {
            int s = ei[e];
            int d = ei[NE + e];
            int bkt = d >> BKTSHIFT;
            int dl = d & ((1 << BKTSHIFT) - 1);
            float a[5];
            #pragma unroll
            for (int kk = 0; kk < 5; ++kk) a[kk] = edge_attr[e * 5 + kk];
            float v0 = 0.f, v1 = 0.f, v2 = 0.f, v3 = 0.f, v4 = 0.f;
            #pragma unroll
            for (int kk = 0; kk < 5; ++kk) {
                v0 += a[kk] * we1s[kk * 4 + 0];
                v1 += a[kk] * we1s[kk * 4 + 1];
                v2 += a[kk] * we1s[kk * 4 + 2];
                v3 += a[kk] * we1s[kk * 4 + 3];
                v4 += a[kk] * we2s[kk];
            }
            unsigned u01 = (unsigned)f2bf(v0) | ((unsigned)f2bf(v1) << 16);
            unsigned u23 = (unsigned)f2bf(v2) | ((unsigned)f2bf(v3) << 16);
            unsigned pk = (unsigned)s | ((unsigned)dl << 17);   // src<2^17, dl<512
            rec[k] = make_float4(__uint_as_float(pk), __uint_as_float(u01),
                                 __uint_as_float(u23), v4);
            bk[k] = bkt;
            rk[k] = atomicAdd(&hcnt[bkt], 1);
        }
    }
    __syncthreads();
    if (t < NBKT && hcnt[t] > 0) hbase[t] = atomicAdd(&bucket_cnt[t * 16], hcnt[t]);
    __syncthreads();
    #pragma unroll
    for (int k = 0; k < 4; ++k) {
        if (bk[k] >= 0) {
            int pos = hbase[bk[k]] + rk[k];
            if (pos < BKTCAP)
                bucketbuf[(size_t)bk[k] * BKTCAP + pos] = rec[k];
        }
    }
}

// ---------------------------------------------------------------------------
// K_SORTFILL: one block per bucket. LDS histogram -> deg/erow coalesced;
// records scattered to final CSR slots within an ~82KB L2-resident region.
__global__ void __launch_bounds__(1024) k_sortfill(
    const int* __restrict__ bucket_cnt, const float4* __restrict__ bucketbuf,
    float4* __restrict__ rec2, int* __restrict__ deg, int* __restrict__ erow) {
    __shared__ int pref[256];
    __shared__ int hist[512];
    __shared__ int hoff[512];
    int t = threadIdx.x;
    int b = blockIdx.x;
    if (t < 256) pref[t] = (t < NBKT) ? bucket_cnt[t * 16] : 0;
    if (t < 512) hist[t] = 0;
    __syncthreads();
    for (int off = 1; off < 256; off <<= 1) {
        int v = 0;
        if (t < 256 && t >= off) v = pref[t - off];
        __syncthreads();
        if (t < 256) pref[t] += v;
        __syncthreads();
    }
    int count = bucket_cnt[b * 16];
    if (count > BKTCAP) count = BKTCAP;
    int region = (b == 0) ? 0 : pref[b - 1];
    float4 rv[6];
    int dlv[6], rrv[6];
    #pragma unroll
    for (int k = 0; k < 6; ++k) {
        int i = k * 1024 + t;
        dlv[k] = -1;
        if (i < count) {
            float4 p = bucketbuf[(size_t)b * BKTCAP + i];
            int dl = (int)(__float_as_uint(p.x) >> 17);
            p.x = __uint_as_float(__float_as_uint(p.x) & 0x1FFFFu);  // keep src
            rv[k] = p;
            dlv[k] = dl;
            rrv[k] = atomicAdd(&hist[dl], 1);
        }
    }
    __syncthreads();
    if (t < 512) hoff[t] = hist[t];
    __syncthreads();
    for (int off = 1; off < 512; off <<= 1) {
        int v = 0;
        if (t < 512 && t >= off) v = hoff[t - off];
        __syncthreads();
        if (t < 512) hoff[t] += v;
        __syncthreads();
    }
    #pragma unroll
    for (int k = 0; k < 6; ++k) {
        if (dlv[k] >= 0) {
            int pos = region + hoff[dlv[k]] - hist[dlv[k]] + rrv[k];
            rec2[pos] = rv[k];
        }
    }
    int n = (b << BKTSHIFT) + t;
    if (t < 512 && n < NN) {
        deg[n] = hist[t];
        erow[n] = region + hoff[t] - hist[t];
    }
}

// ---------------------------------------------------------------------------
// K6: GAT layer 1. One wave = 2 nodes; lane owns dims {2j,2j+1}.
__global__ void __launch_bounds__(256) k_agg1(
    const int* __restrict__ erow, const int* __restrict__ deg,
    const float4* __restrict__ rec2,
    const float* __restrict__ as1, const float* __restrict__ ad1,
    const unsigned short* __restrict__ h1b, const float* __restrict__ c1_b,
    unsigned short* __restrict__ x1b, float* __restrict__ selfae2) {
    __shared__ float pT[4][2][32][4];
    __shared__ int   srcT[4][2][32];
    int wid = threadIdx.x >> 6;
    int lane = threadIdx.x & 63;
    int half = lane >> 5;
    int j = lane & 31;
    int h = j >> 3;
    int n = blockIdx.x * 8 + wid * 2 + half;
    int base = erow[n];
    int dg   = deg[n];
    const float4* as1v4 = (const float4*)as1;
    const float4* ad1v4 = (const float4*)ad1;
    float4 adv = ad1v4[n];
    float4 asv = as1v4[n];
    unsigned uself = *(const unsigned*)(h1b + (unsigned)n * 64u + 2u * (unsigned)j);

    float ssum = 0.f, acc0 = 0.f, acc1 = 0.f;
    float aes0 = 0.f, aes1 = 0.f, aes2 = 0.f, aes3 = 0.f, ae2sum = 0.f;

    for (int i0 = 0; i0 < dg; i0 += 32) {
        int clen = dg - i0; if (clen > 32) clen = 32;
        int idx = i0 + j;
        if (idx < dg) {
            float4 r = rec2[base + idx];
            int s = __float_as_int(r.x);
            unsigned u01 = __float_as_uint(r.y), u23 = __float_as_uint(r.z);
            float ae0  = bf2f((unsigned short)u01);
            float ae1v = bf2f((unsigned short)(u01 >> 16));
            float ae2v = bf2f((unsigned short)u23);
            float ae3v = bf2f((unsigned short)(u23 >> 16));
            float4 av = as1v4[s];
            float l0 = av.x + adv.x + ae0;  l0 = l0 > 0.f ? l0 : 0.2f * l0;
            float l1 = av.y + adv.y + ae1v; l1 = l1 > 0.f ? l1 : 0.2f * l1;
            float l2 = av.z + adv.z + ae2v; l2 = l2 > 0.f ? l2 : 0.2f * l2;
            float l3 = av.w + adv.w + ae3v; l3 = l3 > 0.f ? l3 : 0.2f * l3;
            float4 q = make_float4(__expf(l0), __expf(l1), __expf(l2), __expf(l3));
            *(float4*)&pT[wid][half][j][0] = q;
            srcT[wid][half][j] = s;
            aes0 += ae0; aes1 += ae1v; aes2 += ae2v; aes3 += ae3v;
            ae2sum += r.w;
        }
        int i = 0;
        for (; i + 4 <= clen; i += 4) {
            int s0 = srcT[wid][half][i],     s1 = srcT[wid][half][i + 1];
            int s2 = srcT[wid][half][i + 2], s3 = srcT[wid][half][i + 3];
            float q0 = pT[wid][half][i][h],     q1 = pT[wid][half][i + 1][h];
            float q2 = pT[wid][half][i + 2][h], q3 = pT[wid][half][i + 3][h];
            unsigned g0 = *(const unsigned*)(h1b + (unsigned)s0 * 64u + 2u * (unsigned)j);
            unsigned g1 = *(const unsigned*)(h1b + (unsigned)s1 * 64u + 2u * (unsigned)j);
            unsigned g2 = *(const unsigned*)(h1b + (unsigned)s2 * 64u + 2u * (unsigned)j);
            unsigned g3 = *(const unsigned*)(h1b + (unsigned)s3 * 64u + 2u * (unsigned)j);
            ssum += (q0 + q1) + (q2 + q3);
            acc0 = fmaf(q0, bf2f((unsigned short)g0),
                   fmaf(q1, bf2f((unsigned short)g1),
                   fmaf(q2, bf2f((unsigned short)g2),
                   fmaf(q3, bf2f((unsigned short)g3), acc0))));
            acc1 = fmaf(q0, bf2f((unsigned short)(g0 >> 16)),
                   fmaf(q1, bf2f((unsigned short)(g1 >> 16)),
                   fmaf(q2, bf2f((unsigned short)(g2 >> 16)),
                   fmaf(q3, bf2f((unsigned short)(g3 >> 16)), acc1))));
        }
        for (; i < clen; ++i) {
            int s0 = srcT[wid][half][i];
            float q0 = pT[wid][half][i][h];
            unsigned g0 = *(const unsigned*)(h1b + (unsigned)s0 * 64u + 2u * (unsigned)j);
            ssum += q0;
            acc0 = fmaf(q0, bf2f((unsigned short)g0), acc0);
            acc1 = fmaf(q0, bf2f((unsigned short)(g0 >> 16)), acc1);
        }
    }
    #pragma unroll
    for (int m = 1; m < 32; m <<= 1) {
        aes0 += __shfl_xor(aes0, m);
        aes1 += __shfl_xor(aes1, m);
        aes2 += __shfl_xor(aes2, m);
        aes3 += __shfl_xor(aes3, m);
        ae2sum += __shfl_xor(ae2sum, m);
    }
    float invd = 1.f / fmaxf((float)dg, 1.f);
    float aesh = (h == 0) ? aes0 : (h == 1) ? aes1 : (h == 2) ? aes2 : aes3;
    float adh  = (h == 0) ? adv.x : (h == 1) ? adv.y : (h == 2) ? adv.z : adv.w;
    float ash  = (h == 0) ? asv.x : (h == 1) ? asv.y : (h == 2) ? asv.z : asv.w;
    float ls = ash + adh + aesh * invd;
    ls = ls > 0.f ? ls : 0.2f * ls;
    float ps = __expf(ls);
    ssum += ps;
    acc0 = fmaf(ps, bf2f((unsigned short)uself), acc0);
    acc1 = fmaf(ps, bf2f((unsigned short)(uself >> 16)), acc1);
    if (lane == 0) selfae2[n] = ae2sum * invd;
    if (lane == 32) selfae2[n] = ae2sum * invd;   // half=1's node
    float inv_s = 1.f / ssum;
    float x0 = acc0 * inv_s + c1_b[2 * j];
    float x1 = acc1 * inv_s + c1_b[2 * j + 1];
    x0 = (x0 > 0.f) ? x0 : (__expf(x0) - 1.f);   // ELU
    x1 = (x1 > 0.f) ? x1 : (__expf(x1) - 1.f);
    unsigned w = (unsigned)f2bf(x0) | ((unsigned)f2bf(x1) << 16);
    *(unsigned*)(x1b + (unsigned)n * 64u + 2u * (unsigned)j) = w;
}

// ---------------------------------------------------------------------------
// K6.5: wave-cooperative GEMV h2 = x1 @ c2_W (64->32) + as2/ad2 scalars.
__global__ void __launch_bounds__(256) k_mid(
    const unsigned short* __restrict__ x1b, const float* __restrict__ c2_W,
    const float* __restrict__ c2_as, const float* __restrict__ c2_ad,
    unsigned short* __restrict__ h2b, float* __restrict__ as2,
    float* __restrict__ ad2) {
    int wave = (blockIdx.x * 256 + threadIdx.x) >> 6;   // 50000 waves
    int lane = threadIdx.x & 63;
    int half = lane >> 5, j = lane & 31;
    int n = wave * 2 + half;
    unsigned u = *(const unsigned*)(x1b + (unsigned)n * 64u + j * 2u);
    float acc = 0.f;
    #pragma unroll
    for (int t = 0; t < 32; ++t) {
        unsigned xu = (unsigned)__shfl((int)u, half * 32 + t, 64);
        float x0 = bf2f((unsigned short)xu);
        float x1 = bf2f((unsigned short)(xu >> 16));
        acc = fmaf(x0, c2_W[(2 * t) * 32 + j], acc);
        acc = fmaf(x1, c2_W[(2 * t + 1) * 32 + j], acc);
    }
    float a = acc * c2_as[j], b = acc * c2_ad[j];
    #pragma unroll
    for (int m = 16; m > 0; m >>= 1) {
        a += __shfl_xor(a, m, 64);
        b += __shfl_xor(b, m, 64);
    }
    if (j == 0) { as2[n] = a; ad2[n] = b; }
    h2b[(unsigned)n * 32u + j] = f2bf(acc);
}

// ---------------------------------------------------------------------------
// K7: GAT layer 2, one 32-lane group per dst; self via selfae2.
__global__ void __launch_bounds__(256) k_agg2(
    const int* __restrict__ erow, const int* __restrict__ deg,
    const float4* __restrict__ rec2, const float* __restrict__ as2,
    const float* __restrict__ ad2, const float* __restrict__ selfae2,
    const unsigned short* __restrict__ h2b, const float* __restrict__ c2_b,
    float* __restrict__ out) {
    __shared__ float2 spT[8][32];
    int t = threadIdx.x;
    int half = t >> 5;
    int l32 = t & 31;
    int n = blockIdx.x * 8 + half;
    int base = erow[n];
    int dg = deg[n];
    float ad2n = ad2[n];
    float ssum = 0.f, acc = 0.f;
    for (int i0 = 0; i0 < dg; i0 += 32) {
        int clen = dg - i0; if (clen > 32) clen = 32;
        int idx = i0 + l32;
        float p = 0.f; int s = 0;
        if (idx < dg) {
            float4 r = rec2[base + idx];
            s = __float_as_int(r.x);
            float l = as2[s] + ad2n + r.w;
            l = l > 0.f ? l : 0.2f * l;
            p = __expf(l);
        }
        ssum += p;
        spT[half][l32] = make_float2(__int_as_float(s), p);
        int i = 0;
        for (; i + 4 <= clen; i += 4) {
            float2 e0 = spT[half][i],     e1 = spT[half][i + 1];
            float2 e2 = spT[half][i + 2], e3 = spT[half][i + 3];
            int s0 = __float_as_int(e0.x), s1 = __float_as_int(e1.x);
            int s2 = __float_as_int(e2.x), s3 = __float_as_int(e3.x);
            float g0 = bf2f(h2b[(unsigned)s0 * 32u + l32]);
            float g1 = bf2f(h2b[(unsigned)s1 * 32u + l32]);
            float g2 = bf2f(h2b[(unsigned)s2 * 32u + l32]);
            float g3 = bf2f(h2b[(unsigned)s3 * 32u + l32]);
            acc = fmaf(e0.y, g0, fmaf(e1.y, g1, fmaf(e2.y, g2, fmaf(e3.y, g3, acc))));
        }
        for (; i < clen; ++i) {
            float2 e0 = spT[half][i];
            int s0 = __float_as_int(e0.x);
            acc = fmaf(e0.y, bf2f(h2b[(unsigned)s0 * 32u + l32]), acc);
        }
    }
    #pragma unroll
    for (int m = 1; m < 32; m <<= 1) ssum += __shfl_xor(ssum, m, 32);
    float ls = as2[n] + ad2n + selfae2[n];
    ls = ls > 0.f ? ls : 0.2f * ls;
    float ps = __expf(ls);
    ssum += ps;
    acc = fmaf(ps, bf2f(h2b[(unsigned)n * 32u + l32]), acc);
    out[(size_t)n * 32 + l32] = acc / ssum + c2_b[l32];
}

// ---------------------------------------------------------------------------
extern "C" void kernel_launch(void* const* d_in, const int* in_sizes, int n_in,
                              void* d_out, int out_size, void* d_ws, size_t ws_size,
                              hipStream_t stream) {
    const int*   edge_index  = (const int*)  d_in[0];
    const float* edge_attr   = (const float*)d_in[1];
    const float* pol_feat    = (const float*)d_in[2];
    const int*   state_ids   = (const int*)  d_in[3];
    const int*   sector_ids  = (const int*)  d_in[4];
    const int*   industry_ids= (const int*)  d_in[5];
    const float* comp_scalar = (const float*)d_in[6];
    const float* pol_W   = (const float*)d_in[7];
    const float* pol_b   = (const float*)d_in[8];
    const float* state_E = (const float*)d_in[9];
    const float* sector_E= (const float*)d_in[10];
    const float* industry_E=(const float*)d_in[11];
    const float* comp_W  = (const float*)d_in[12];
    const float* comp_b  = (const float*)d_in[13];
    const float* comm_E  = (const float*)d_in[14];
    const float* ln_g    = (const float*)d_in[15];
    const float* ln_b    = (const float*)d_in[16];
    const float* c1_W    = (const float*)d_in[17];
    const float* c1_as   = (const float*)d_in[18];
    const float* c1_ad   = (const float*)d_in[19];
    const float* c1_eW   = (const float*)d_in[20];
    const float* c1_ae   = (const float*)d_in[21];
    const float* c1_b    = (const float*)d_in[22];
    const float* c2_W    = (const float*)d_in[23];
    const float* c2_as   = (const float*)d_in[24];
    const float* c2_ad   = (const float*)d_in[25];
    const float* c2_eW   = (const float*)d_in[26];
    const float* c2_ae   = (const float*)d_in[27];
    const float* c2_b    = (const float*)d_in[28];
    float* out = (float*)d_out;

    char* ws = (char*)d_ws;
    size_t off = 0;
    auto alloc = [&](size_t bytes) { void* p = ws + off; off += (bytes + 255) & ~(size_t)255; return p; };
    int*    bucket_cnt = (int*)   alloc((size_t)NBKT * 16 * 4);  // 64B-strided
    float4* bucketbuf  = (float4*)alloc((size_t)NBKT * BKTCAP * 16);
    float4* rec2       = (float4*)alloc((size_t)NE * 16);
    int*    deg        = (int*)   alloc(NN * 4);
    int*    erow       = (int*)   alloc(NN * 4);
    float*  selfae2    = (float*) alloc(NN * 4);
    unsigned short* h1b = (unsigned short*)alloc((size_t)NN * 64 * 2);
    float* as1       = (float*)alloc((size_t)NN * 4 * 4);
    float* ad1       = (float*)alloc((size_t)NN * 4 * 4);
    unsigned short* x1b = (unsigned short*)alloc((size_t)NN * 64 * 2);
    unsigned short* h2b = (unsigned short*)alloc((size_t)NN * 32 * 2);
    float* as2       = (float*)alloc(NN * 4);
    float* ad2       = (float*)alloc(NN * 4);
    (void)ws_size; (void)in_sizes; (void)n_in; (void)out_size;

    k_feat<<<NFEATBLK, 256, 0, stream>>>(
        pol_feat, state_ids, sector_ids, industry_ids, comp_scalar,
        pol_W, pol_b, state_E, sector_E, industry_E, comp_W, comp_b, comm_E,
        ln_g, ln_b, c1_W, c1_as, c1_ad, h1b, as1, ad1, bucket_cnt);
    k_bucket<<<KA_BLOCKS, 1024, 0, stream>>>(
        edge_index, edge_attr, c1_eW, c1_ae, c2_eW, c2_ae, bucket_cnt, bucketbuf);
    k_sortfill<<<NBKT, 1024, 0, stream>>>(
        bucket_cnt, bucketbuf, rec2, deg, erow);
    k_agg1<<<NN / 8, 256, 0, stream>>>(
        erow, deg, rec2, as1, ad1, h1b, c1_b, x1b, selfae2);
    k_mid<<<(NN / 2) / 4, 256, 0, stream>>>(
        x1b, c2_W, c2_as, c2_ad, h2b, as2, ad2);
    k_agg2<<<NN / 8, 256, 0, stream>>>(
        erow, deg, rec2, as2, ad2, selfae2, h2b, c2_b, out);
}

// Round 14
// 159.644 us; speedup vs baseline: 1.2767x; 1.0702x over previous
//
#include <hip/hip_runtime.h>
#include <math.h>

#define NPOL   1000
#define NTICK  98000
#define NCOMM  1000
#define NN     100000
#define NE     1000000

#define BKTSHIFT 9       // 512 nodes per bucket
#define NBKT     196     // ceil(NN/512)
#define BKTCAP   6144    // mean 5120 -> large headroom
#define KA_EPB   4096    // edges per bucket block
#define KA_BLOCKS 245    // ceil(NE/4096)
#define FEATBLKS  391    // ceil(NN*4/1024)

__device__ __forceinline__ unsigned short f2bf(float v) {
    unsigned u = __float_as_uint(v);
    u += 0x7FFFu + ((u >> 16) & 1u);          // round-to-nearest-even
    return (unsigned short)(u >> 16);
}
__device__ __forceinline__ float bf2f(unsigned short s) {
    return __uint_as_float(((unsigned)s) << 16);
}

// ---------------------------------------------------------------------------
__global__ void k_zero(int* __restrict__ bucket_cnt) {
    for (int i = threadIdx.x; i < NBKT * 16; i += 1024) bucket_cnt[i] = 0;
}

// ---------------------------------------------------------------------------
// K_FEATBUCKET: blocks [0,KA_BLOCKS) = edge bucketing (memory/atomic-bound);
// blocks [KA_BLOCKS,..) = node features->LN->h1->as1/ad1 (LDS/VALU-bound).
// 245 bucket blocks occupy ~half the CUs, so feat blocks co-execute (the R9
// block-split failed because its first segment saturated the whole machine).
__global__ void __launch_bounds__(1024) k_featbucket(
    const int* __restrict__ ei, const float* __restrict__ edge_attr,
    const float* __restrict__ c1_eW, const float* __restrict__ c1_ae,
    const float* __restrict__ c2_eW, const float* __restrict__ c2_ae,
    int* __restrict__ bucket_cnt, float4* __restrict__ bucketbuf,
    const float* __restrict__ pol_feat, const int* __restrict__ state_ids,
    const int* __restrict__ sector_ids, const int* __restrict__ industry_ids,
    const float* __restrict__ comp_scalar,
    const float* __restrict__ pol_W, const float* __restrict__ pol_b,
    const float* __restrict__ state_E, const float* __restrict__ sector_E,
    const float* __restrict__ industry_E, const float* __restrict__ comp_W,
    const float* __restrict__ comp_b, const float* __restrict__ comm_E,
    const float* __restrict__ ln_g, const float* __restrict__ ln_b,
    const float* __restrict__ c1_W, const float* __restrict__ c1_as,
    const float* __restrict__ c1_ad,
    unsigned short* __restrict__ h1b, float* __restrict__ as1,
    float* __restrict__ ad1) {
    int t = threadIdx.x;
    if (blockIdx.x < KA_BLOCKS) {
        // ---------------- bucket part ----------------
        __shared__ float we1s[20];
        __shared__ float we2s[5];
        __shared__ int hcnt[NBKT];
        __shared__ int hbase[NBKT];
        if (t < 20) {
            int d = t >> 2, h = t & 3;
            float s = 0.f;
            for (int f = 0; f < 16; ++f) s += c1_eW[d * 64 + h * 16 + f] * c1_ae[h * 16 + f];
            we1s[t] = s;
        } else if (t >= 32 && t < 37) {
            int d = t - 32;
            float s = 0.f;
            for (int f = 0; f < 32; ++f) s += c2_eW[d * 32 + f] * c2_ae[f];
            we2s[d] = s;
        }
        if (t < NBKT) hcnt[t] = 0;
        __syncthreads();
        int e0 = blockIdx.x * KA_EPB + t;
        int bk[4], rk[4];
        float4 rec[4];
        #pragma unroll
        for (int k = 0; k < 4; ++k) {
            int e = e0 + k * 1024;
            bk[k] = -1;
            if (e < NE) {
                int s = ei[e];
                int d = ei[NE + e];
                int bkt = d >> BKTSHIFT;
                int dl = d & ((1 << BKTSHIFT) - 1);
                float a[5];
                #pragma unroll
                for (int kk = 0; kk < 5; ++kk) a[kk] = edge_attr[e * 5 + kk];
                float v0 = 0.f, v1 = 0.f, v2 = 0.f, v3 = 0.f, v4 = 0.f;
                #pragma unroll
                for (int kk = 0; kk < 5; ++kk) {
                    v0 += a[kk] * we1s[kk * 4 + 0];
                    v1 += a[kk] * we1s[kk * 4 + 1];
                    v2 += a[kk] * we1s[kk * 4 + 2];
                    v3 += a[kk] * we1s[kk * 4 + 3];
                    v4 += a[kk] * we2s[kk];
                }
                unsigned u01 = (unsigned)f2bf(v0) | ((unsigned)f2bf(v1) << 16);
                unsigned u23 = (unsigned)f2bf(v2) | ((unsigned)f2bf(v3) << 16);
                unsigned pk = (unsigned)s | ((unsigned)dl << 17);
                rec[k] = make_float4(__uint_as_float(pk), __uint_as_float(u01),
                                     __uint_as_float(u23), v4);
                bk[k] = bkt;
                rk[k] = atomicAdd(&hcnt[bkt], 1);
            }
        }
        __syncthreads();
        if (t < NBKT && hcnt[t] > 0) hbase[t] = atomicAdd(&bucket_cnt[t * 16], hcnt[t]);
        __syncthreads();
        #pragma unroll
        for (int k = 0; k < 4; ++k) {
            if (bk[k] >= 0) {
                int pos = hbase[bk[k]] + rk[k];
                if (pos < BKTCAP)
                    bucketbuf[(size_t)bk[k] * BKTCAP + pos] = rec[k];
            }
        }
        return;
    }
    // ---------------- feat part ----------------
    __shared__ float sW1[2048];
    __shared__ float sCompW[544];
    __shared__ float sPolW[224];
    __shared__ float sAs[64], sAd[64];
    __shared__ float sLg[32], sLb[32], sPb[32], sCb[32];
    for (int i = t; i < 2048; i += 1024) sW1[i] = c1_W[i];
    if (t < 544) sCompW[t] = comp_W[t];
    if (t >= 544 && t < 768) sPolW[t - 544] = pol_W[t - 544];
    if (t >= 768 && t < 832) { sAs[t - 768] = c1_as[t - 768]; sAd[t - 768] = c1_ad[t - 768]; }
    if (t >= 832 && t < 864) {
        int i = t - 832;
        sLg[i] = ln_g[i]; sLb[i] = ln_b[i]; sPb[i] = pol_b[i]; sCb[i] = comp_b[i];
    }
    __syncthreads();
    int tid = (blockIdx.x - KA_BLOCKS) * 1024 + t;
    if (tid >= 4 * NN) return;
    int n = tid >> 2, q = tid & 3, jb = q * 8;
    float x[8];
    if (n < NPOL) {
        float f[7];
        #pragma unroll
        for (int i = 0; i < 7; ++i) f[i] = pol_feat[n * 7 + i];
        int sid = state_ids[n];
        #pragma unroll
        for (int jj = 0; jj < 8; ++jj) {
            int j = jb + jj;
            float v = sPb[j];
            #pragma unroll
            for (int i = 0; i < 7; ++i) v += f[i] * sPolW[i * 32 + j];
            v = v > 0.f ? v : 0.f;
            x[jj] = v + state_E[sid * 32 + j];
        }
    } else if (n < NPOL + NTICK) {
        int tt = n - NPOL;
        float f[17];
        int sec = sector_ids[tt], ind = industry_ids[tt];
        #pragma unroll
        for (int i = 0; i < 8; ++i) { f[i] = sector_E[sec * 8 + i]; f[8 + i] = industry_E[ind * 8 + i]; }
        f[16] = comp_scalar[tt];
        #pragma unroll
        for (int jj = 0; jj < 8; ++jj) {
            int j = jb + jj;
            float v = sCb[j];
            #pragma unroll
            for (int i = 0; i < 17; ++i) v += f[i] * sCompW[i * 32 + j];
            x[jj] = v > 0.f ? v : 0.f;
        }
    } else {
        int c = n - (NPOL + NTICK);
        float4 a = *(const float4*)&comm_E[c * 32 + jb];
        float4 b = *(const float4*)&comm_E[c * 32 + jb + 4];
        x[0] = a.x; x[1] = a.y; x[2] = a.z; x[3] = a.w;
        x[4] = b.x; x[5] = b.y; x[6] = b.z; x[7] = b.w;
    }
    float s1 = 0.f;
    #pragma unroll
    for (int jj = 0; jj < 8; ++jj) s1 += x[jj];
    s1 += __shfl_xor(s1, 1); s1 += __shfl_xor(s1, 2);
    float mu = s1 * (1.f / 32.f);
    float s2 = 0.f;
    #pragma unroll
    for (int jj = 0; jj < 8; ++jj) { float dd = x[jj] - mu; s2 += dd * dd; }
    s2 += __shfl_xor(s2, 1); s2 += __shfl_xor(s2, 2);
    float inv = rsqrtf(s2 * (1.f / 32.f) + 1e-5f);
    #pragma unroll
    for (int jj = 0; jj < 8; ++jj) x[jj] = (x[jj] - mu) * inv * sLg[jb + jj] + sLb[jb + jj];
    float4 acc0 = {0,0,0,0}, acc1 = {0,0,0,0}, acc2 = {0,0,0,0}, acc3 = {0,0,0,0};
    int qb = (t & 63) & ~3;
    int jc = q * 16;
    #pragma unroll
    for (int p = 0; p < 4; ++p) {
        #pragma unroll
        for (int jj = 0; jj < 8; ++jj) {
            float xs = __shfl(x[jj], qb + p, 64);
            const float4* wr = (const float4*)&sW1[(p * 8 + jj) * 64 + jc];
            float4 w0 = wr[0], w1 = wr[1], w2 = wr[2], w3 = wr[3];
            acc0.x = fmaf(xs, w0.x, acc0.x); acc0.y = fmaf(xs, w0.y, acc0.y);
            acc0.z = fmaf(xs, w0.z, acc0.z); acc0.w = fmaf(xs, w0.w, acc0.w);
            acc1.x = fmaf(xs, w1.x, acc1.x); acc1.y = fmaf(xs, w1.y, acc1.y);
            acc1.z = fmaf(xs, w1.z, acc1.z); acc1.w = fmaf(xs, w1.w, acc1.w);
            acc2.x = fmaf(xs, w2.x, acc2.x); acc2.y = fmaf(xs, w2.y, acc2.y);
            acc2.z = fmaf(xs, w2.z, acc2.z); acc2.w = fmaf(xs, w2.w, acc2.w);
            acc3.x = fmaf(xs, w3.x, acc3.x); acc3.y = fmaf(xs, w3.y, acc3.y);
            acc3.z = fmaf(xs, w3.z, acc3.z); acc3.w = fmaf(xs, w3.w, acc3.w);
        }
    }
    const float4* asv = (const float4*)sAs;
    const float4* adv = (const float4*)sAd;
    float4 a0 = asv[q * 4], a1 = asv[q * 4 + 1], a2 = asv[q * 4 + 2], a3 = asv[q * 4 + 3];
    float4 b0 = adv[q * 4], b1v = adv[q * 4 + 1], b2v = adv[q * 4 + 2], b3 = adv[q * 4 + 3];
    float av = acc0.x * a0.x + acc0.y * a0.y + acc0.z * a0.z + acc0.w * a0.w
             + acc1.x * a1.x + acc1.y * a1.y + acc1.z * a1.z + acc1.w * a1.w
             + acc2.x * a2.x + acc2.y * a2.y + acc2.z * a2.z + acc2.w * a2.w
             + acc3.x * a3.x + acc3.y * a3.y + acc3.z * a3.z + acc3.w * a3.w;
    float dv = acc0.x * b0.x + acc0.y * b0.y + acc0.z * b0.z + acc0.w * b0.w
             + acc1.x * b1v.x + acc1.y * b1v.y + acc1.z * b1v.z + acc1.w * b1v.w
             + acc2.x * b2v.x + acc2.y * b2v.y + acc2.z * b2v.z + acc2.w * b2v.w
             + acc3.x * b3.x + acc3.y * b3.y + acc3.z * b3.z + acc3.w * b3.w;
    as1[tid] = av;
    ad1[tid] = dv;
    uint4 w1o, w2o;
    w1o.x = (unsigned)f2bf(acc0.x) | ((unsigned)f2bf(acc0.y) << 16);
    w1o.y = (unsigned)f2bf(acc0.z) | ((unsigned)f2bf(acc0.w) << 16);
    w1o.z = (unsigned)f2bf(acc1.x) | ((unsigned)f2bf(acc1.y) << 16);
    w1o.w = (unsigned)f2bf(acc1.z) | ((unsigned)f2bf(acc1.w) << 16);
    w2o.x = (unsigned)f2bf(acc2.x) | ((unsigned)f2bf(acc2.y) << 16);
    w2o.y = (unsigned)f2bf(acc2.z) | ((unsigned)f2bf(acc2.w) << 16);
    w2o.z = (unsigned)f2bf(acc3.x) | ((unsigned)f2bf(acc3.y) << 16);
    w2o.w = (unsigned)f2bf(acc3.z) | ((unsigned)f2bf(acc3.w) << 16);
    unsigned short* hp = h1b + (unsigned)n * 64u + (unsigned)jc;
    *(uint4*)hp = w1o;
    *(uint4*)(hp + 8) = w2o;
}

// ---------------------------------------------------------------------------
// K_SORTFILL: one block per bucket (unchanged from R13).
__global__ void __launch_bounds__(1024) k_sortfill(
    const int* __restrict__ bucket_cnt, const float4* __restrict__ bucketbuf,
    float4* __restrict__ rec2, int* __restrict__ deg, int* __restrict__ erow) {
    __shared__ int pref[256];
    __shared__ int hist[512];
    __shared__ int hoff[512];
    int t = threadIdx.x;
    int b = blockIdx.x;
    if (t < 256) pref[t] = (t < NBKT) ? bucket_cnt[t * 16] : 0;
    if (t < 512) hist[t] = 0;
    __syncthreads();
    for (int off = 1; off < 256; off <<= 1) {
        int v = 0;
        if (t < 256 && t >= off) v = pref[t - off];
        __syncthreads();
        if (t < 256) pref[t] += v;
        __syncthreads();
    }
    int count = bucket_cnt[b * 16];
    if (count > BKTCAP) count = BKTCAP;
    int region = (b == 0) ? 0 : pref[b - 1];
    float4 rv[6];
    int dlv[6], rrv[6];
    #pragma unroll
    for (int k = 0; k < 6; ++k) {
        int i = k * 1024 + t;
        dlv[k] = -1;
        if (i < count) {
            float4 p = bucketbuf[(size_t)b * BKTCAP + i];
            int dl = (int)(__float_as_uint(p.x) >> 17);
            p.x = __uint_as_float(__float_as_uint(p.x) & 0x1FFFFu);
            rv[k] = p;
            dlv[k] = dl;
            rrv[k] = atomicAdd(&hist[dl], 1);
        }
    }
    __syncthreads();
    if (t < 512) hoff[t] = hist[t];
    __syncthreads();
    for (int off = 1; off < 512; off <<= 1) {
        int v = 0;
        if (t < 512 && t >= off) v = hoff[t - off];
        __syncthreads();
        if (t < 512) hoff[t] += v;
        __syncthreads();
    }
    #pragma unroll
    for (int k = 0; k < 6; ++k) {
        if (dlv[k] >= 0) {
            int pos = region + hoff[dlv[k]] - hist[dlv[k]] + rrv[k];
            rec2[pos] = rv[k];
        }
    }
    int n = (b << BKTSHIFT) + t;
    if (t < 512 && n < NN) {
        deg[n] = hist[t];
        erow[n] = region + hoff[t] - hist[t];
    }
}

// ---------------------------------------------------------------------------
// K_AGG1M: GAT layer 1 aggregation (2 nodes/wave) + fused k_mid epilogue:
// h2 = x1 @ c2_W wave-cooperative GEMV, as2/ad2 reduce, h2b write. The x1b
// buffer round trip (25.6MB) and one launch are eliminated; the GEMV consumes
// the identical bf16-packed w, so numerics are unchanged.
__global__ void __launch_bounds__(256) k_agg1m(
    const int* __restrict__ erow, const int* __restrict__ deg,
    const float4* __restrict__ rec2,
    const float* __restrict__ as1, const float* __restrict__ ad1,
    const unsigned short* __restrict__ h1b, const float* __restrict__ c1_b,
    const float* __restrict__ c2_W, const float* __restrict__ c2_as,
    const float* __restrict__ c2_ad,
    unsigned short* __restrict__ h2b, float* __restrict__ as2,
    float* __restrict__ ad2, float* __restrict__ selfae2) {
    __shared__ float pT[4][2][32][4];
    __shared__ int   srcT[4][2][32];
    int wid = threadIdx.x >> 6;
    int lane = threadIdx.x & 63;
    int half = lane >> 5;
    int j = lane & 31;
    int h = j >> 3;
    int n = blockIdx.x * 8 + wid * 2 + half;
    int base = erow[n];
    int dg   = deg[n];
    const float4* as1v4 = (const float4*)as1;
    const float4* ad1v4 = (const float4*)ad1;
    float4 adv = ad1v4[n];
    float4 asv = as1v4[n];
    unsigned uself = *(const unsigned*)(h1b + (unsigned)n * 64u + 2u * (unsigned)j);

    float ssum = 0.f, acc0 = 0.f, acc1 = 0.f;
    float aes0 = 0.f, aes1 = 0.f, aes2 = 0.f, aes3 = 0.f, ae2sum = 0.f;

    for (int i0 = 0; i0 < dg; i0 += 32) {
        int clen = dg - i0; if (clen > 32) clen = 32;
        int idx = i0 + j;
        if (idx < dg) {
            float4 r = rec2[base + idx];
            int s = __float_as_int(r.x);
            unsigned u01 = __float_as_uint(r.y), u23 = __float_as_uint(r.z);
            float ae0  = bf2f((unsigned short)u01);
            float ae1v = bf2f((unsigned short)(u01 >> 16));
            float ae2v = bf2f((unsigned short)u23);
            float ae3v = bf2f((unsigned short)(u23 >> 16));
            float4 av = as1v4[s];
            float l0 = av.x + adv.x + ae0;  l0 = l0 > 0.f ? l0 : 0.2f * l0;
            float l1 = av.y + adv.y + ae1v; l1 = l1 > 0.f ? l1 : 0.2f * l1;
            float l2 = av.z + adv.z + ae2v; l2 = l2 > 0.f ? l2 : 0.2f * l2;
            float l3 = av.w + adv.w + ae3v; l3 = l3 > 0.f ? l3 : 0.2f * l3;
            float4 q = make_float4(__expf(l0), __expf(l1), __expf(l2), __expf(l3));
            *(float4*)&pT[wid][half][j][0] = q;
            srcT[wid][half][j] = s;
            aes0 += ae0; aes1 += ae1v; aes2 += ae2v; aes3 += ae3v;
            ae2sum += r.w;
        }
        int i = 0;
        for (; i + 4 <= clen; i += 4) {
            int s0 = srcT[wid][half][i],     s1 = srcT[wid][half][i + 1];
            int s2 = srcT[wid][half][i + 2], s3 = srcT[wid][half][i + 3];
            float q0 = pT[wid][half][i][h],     q1 = pT[wid][half][i + 1][h];
            float q2 = pT[wid][half][i + 2][h], q3 = pT[wid][half][i + 3][h];
            unsigned g0 = *(const unsigned*)(h1b + (unsigned)s0 * 64u + 2u * (unsigned)j);
            unsigned g1 = *(const unsigned*)(h1b + (unsigned)s1 * 64u + 2u * (unsigned)j);
            unsigned g2 = *(const unsigned*)(h1b + (unsigned)s2 * 64u + 2u * (unsigned)j);
            unsigned g3 = *(const unsigned*)(h1b + (unsigned)s3 * 64u + 2u * (unsigned)j);
            ssum += (q0 + q1) + (q2 + q3);
            acc0 = fmaf(q0, bf2f((unsigned short)g0),
                   fmaf(q1, bf2f((unsigned short)g1),
                   fmaf(q2, bf2f((unsigned short)g2),
                   fmaf(q3, bf2f((unsigned short)g3), acc0))));
            acc1 = fmaf(q0, bf2f((unsigned short)(g0 >> 16)),
                   fmaf(q1, bf2f((unsigned short)(g1 >> 16)),
                   fmaf(q2, bf2f((unsigned short)(g2 >> 16)),
                   fmaf(q3, bf2f((unsigned short)(g3 >> 16)), acc1))));
        }
        for (; i < clen; ++i) {
            int s0 = srcT[wid][half][i];
            float q0 = pT[wid][half][i][h];
            unsigned g0 = *(const unsigned*)(h1b + (unsigned)s0 * 64u + 2u * (unsigned)j);
            ssum += q0;
            acc0 = fmaf(q0, bf2f((unsigned short)g0), acc0);
            acc1 = fmaf(q0, bf2f((unsigned short)(g0 >> 16)), acc1);
        }
    }
    #pragma unroll
    for (int m = 1; m < 32; m <<= 1) {
        aes0 += __shfl_xor(aes0, m);
        aes1 += __shfl_xor(aes1, m);
        aes2 += __shfl_xor(aes2, m);
        aes3 += __shfl_xor(aes3, m);
        ae2sum += __shfl_xor(ae2sum, m);
    }
    float invd = 1.f / fmaxf((float)dg, 1.f);
    float aesh = (h == 0) ? aes0 : (h == 1) ? aes1 : (h == 2) ? aes2 : aes3;
    float adh  = (h == 0) ? adv.x : (h == 1) ? adv.y : (h == 2) ? adv.z : adv.w;
    float ash  = (h == 0) ? asv.x : (h == 1) ? asv.y : (h == 2) ? asv.z : asv.w;
    float ls = ash + adh + aesh * invd;
    ls = ls > 0.f ? ls : 0.2f * ls;
    float ps = __expf(ls);
    ssum += ps;
    acc0 = fmaf(ps, bf2f((unsigned short)uself), acc0);
    acc1 = fmaf(ps, bf2f((unsigned short)(uself >> 16)), acc1);
    if (lane == 0) selfae2[n] = ae2sum * invd;
    if (lane == 32) selfae2[n] = ae2sum * invd;
    float inv_s = 1.f / ssum;
    float x0 = acc0 * inv_s + c1_b[2 * j];
    float x1 = acc1 * inv_s + c1_b[2 * j + 1];
    x0 = (x0 > 0.f) ? x0 : (__expf(x0) - 1.f);   // ELU
    x1 = (x1 > 0.f) ? x1 : (__expf(x1) - 1.f);
    unsigned w = (unsigned)f2bf(x0) | ((unsigned)f2bf(x1) << 16);
    // ---- fused k_mid: h2 = x1 @ c2_W (64->32), as2/ad2 ----
    float acc = 0.f;
    #pragma unroll
    for (int tt = 0; tt < 32; ++tt) {
        unsigned xu = (unsigned)__shfl((int)w, half * 32 + tt, 64);
        float xa = bf2f((unsigned short)xu);
        float xb = bf2f((unsigned short)(xu >> 16));
        acc = fmaf(xa, c2_W[(2 * tt) * 32 + j], acc);
        acc = fmaf(xb, c2_W[(2 * tt + 1) * 32 + j], acc);
    }
    float a = acc * c2_as[j], b = acc * c2_ad[j];
    #pragma unroll
    for (int m = 16; m > 0; m >>= 1) {
        a += __shfl_xor(a, m, 64);   // stays within the 32-lane half
        b += __shfl_xor(b, m, 64);
    }
    if (j == 0) { as2[n] = a; ad2[n] = b; }
    h2b[(unsigned)n * 32u + j] = f2bf(acc);
}

// ---------------------------------------------------------------------------
// K7: GAT layer 2, one 32-lane group per dst; self via selfae2. Unchanged.
__global__ void __launch_bounds__(256) k_agg2(
    const int* __restrict__ erow, const int* __restrict__ deg,
    const float4* __restrict__ rec2, const float* __restrict__ as2,
    const float* __restrict__ ad2, const float* __restrict__ selfae2,
    const unsigned short* __restrict__ h2b, const float* __restrict__ c2_b,
    float* __restrict__ out) {
    __shared__ float2 spT[8][32];
    int t = threadIdx.x;
    int half = t >> 5;
    int l32 = t & 31;
    int n = blockIdx.x * 8 + half;
    int base = erow[n];
    int dg = deg[n];
    float ad2n = ad2[n];
    float ssum = 0.f, acc = 0.f;
    for (int i0 = 0; i0 < dg; i0 += 32) {
        int clen = dg - i0; if (clen > 32) clen = 32;
        int idx = i0 + l32;
        float p = 0.f; int s = 0;
        if (idx < dg) {
            float4 r = rec2[base + idx];
            s = __float_as_int(r.x);
            float l = as2[s] + ad2n + r.w;
            l = l > 0.f ? l : 0.2f * l;
            p = __expf(l);
        }
        ssum += p;
        spT[half][l32] = make_float2(__int_as_float(s), p);
        int i = 0;
        for (; i + 4 <= clen; i += 4) {
            float2 e0 = spT[half][i],     e1 = spT[half][i + 1];
            float2 e2 = spT[half][i + 2], e3 = spT[half][i + 3];
            int s0 = __float_as_int(e0.x), s1 = __float_as_int(e1.x);
            int s2 = __float_as_int(e2.x), s3 = __float_as_int(e3.x);
            float g0 = bf2f(h2b[(unsigned)s0 * 32u + l32]);
            float g1 = bf2f(h2b[(unsigned)s1 * 32u + l32]);
            float g2 = bf2f(h2b[(unsigned)s2 * 32u + l32]);
            float g3 = bf2f(h2b[(unsigned)s3 * 32u + l32]);
            acc = fmaf(e0.y, g0, fmaf(e1.y, g1, fmaf(e2.y, g2, fmaf(e3.y, g3, acc))));
        }
        for (; i < clen; ++i) {
            float2 e0 = spT[half][i];
            int s0 = __float_as_int(e0.x);
            acc = fmaf(e0.y, bf2f(h2b[(unsigned)s0 * 32u + l32]), acc);
        }
    }
    #pragma unroll
    for (int m = 1; m < 32; m <<= 1) ssum += __shfl_xor(ssum, m, 32);
    float ls = as2[n] + ad2n + selfae2[n];
    ls = ls > 0.f ? ls : 0.2f * ls;
    float ps = __expf(ls);
    ssum += ps;
    acc = fmaf(ps, bf2f(h2b[(unsigned)n * 32u + l32]), acc);
    out[(size_t)n * 32 + l32] = acc / ssum + c2_b[l32];
}

// ---------------------------------------------------------------------------
extern "C" void kernel_launch(void* const* d_in, const int* in_sizes, int n_in,
                              void* d_out, int out_size, void* d_ws, size_t ws_size,
                              hipStream_t stream) {
    const int*   edge_index  = (const int*)  d_in[0];
    const float* edge_attr   = (const float*)d_in[1];
    const float* pol_feat    = (const float*)d_in[2];
    const int*   state_ids   = (const int*)  d_in[3];
    const int*   sector_ids  = (const int*)  d_in[4];
    const int*   industry_ids= (const int*)  d_in[5];
    const float* comp_scalar = (const float*)d_in[6];
    const float* pol_W   = (const float*)d_in[7];
    const float* pol_b   = (const float*)d_in[8];
    const float* state_E = (const float*)d_in[9];
    const float* sector_E= (const float*)d_in[10];
    const float* industry_E=(const float*)d_in[11];
    const float* comp_W  = (const float*)d_in[12];
    const float* comp_b  = (const float*)d_in[13];
    const float* comm_E  = (const float*)d_in[14];
    const float* ln_g    = (const float*)d_in[15];
    const float* ln_b    = (const float*)d_in[16];
    const float* c1_W    = (const float*)d_in[17];
    const float* c1_as   = (const float*)d_in[18];
    const float* c1_ad   = (const float*)d_in[19];
    const float* c1_eW   = (const float*)d_in[20];
    const float* c1_ae   = (const float*)d_in[21];
    const float* c1_b    = (const float*)d_in[22];
    const float* c2_W    = (const float*)d_in[23];
    const float* c2_as   = (const float*)d_in[24];
    const float* c2_ad   = (const float*)d_in[25];
    const float* c2_eW   = (const float*)d_in[26];
    const float* c2_ae   = (const float*)d_in[27];
    const float* c2_b    = (const float*)d_in[28];
    float* out = (float*)d_out;

    char* ws = (char*)d_ws;
    size_t off = 0;
    auto alloc = [&](size_t bytes) { void* p = ws + off; off += (bytes + 255) & ~(size_t)255; return p; };
    int*    bucket_cnt = (int*)   alloc((size_t)NBKT * 16 * 4);
    float4* bucketbuf  = (float4*)alloc((size_t)NBKT * BKTCAP * 16);
    float4* rec2       = (float4*)alloc((size_t)NE * 16);
    int*    deg        = (int*)   alloc(NN * 4);
    int*    erow       = (int*)   alloc(NN * 4);
    float*  selfae2    = (float*) alloc(NN * 4);
    unsigned short* h1b = (unsigned short*)alloc((size_t)NN * 64 * 2);
    float* as1       = (float*)alloc((size_t)NN * 4 * 4);
    float* ad1       = (float*)alloc((size_t)NN * 4 * 4);
    unsigned short* h2b = (unsigned short*)alloc((size_t)NN * 32 * 2);
    float* as2       = (float*)alloc(NN * 4);
    float* ad2       = (float*)alloc(NN * 4);
    (void)ws_size; (void)in_sizes; (void)n_in; (void)out_size;

    k_zero<<<1, 1024, 0, stream>>>(bucket_cnt);
    k_featbucket<<<KA_BLOCKS + FEATBLKS, 1024, 0, stream>>>(
        edge_index, edge_attr, c1_eW, c1_ae, c2_eW, c2_ae, bucket_cnt, bucketbuf,
        pol_feat, state_ids, sector_ids, industry_ids, comp_scalar,
        pol_W, pol_b, state_E, sector_E, industry_E, comp_W, comp_b, comm_E,
        ln_g, ln_b, c1_W, c1_as, c1_ad, h1b, as1, ad1);
    k_sortfill<<<NBKT, 1024, 0, stream>>>(
        bucket_cnt, bucketbuf, rec2, deg, erow);
    k_agg1m<<<NN / 8, 256, 0, stream>>>(
        erow, deg, rec2, as1, ad1, h1b, c1_b, c2_W, c2_as, c2_ad,
        h2b, as2, ad2, selfae2);
    k_agg2<<<NN / 8, 256, 0, stream>>>(
        erow, deg, rec2, as2, ad2, selfae2, h2b, c2_b, out);
}